// Round 3
// baseline (4768.761 us; speedup 1.0000x reference)
//
#include <hip/hip_runtime.h>
#include <hip/hip_bf16.h>

typedef __hip_bfloat16 bf16;

// ---- problem constants (fixed by the reference file) ----
#define K_NUM_DST 100000
#define K_E       1000000
#define K_UN      200000
#define K_UE      100000
#define K_UT      100000
#define K_DN      172
#define K_DT      100
#define K_DOUT    100
#define K_DKV     200
#define K_DCAT    272
#define K_NEG_SLOPE 0.2f
#define K_LN_EPS    1e-5f

__device__ __forceinline__ float bits2f(unsigned short u){
  union { float f; unsigned int i; } c; c.i = ((unsigned int)u) << 16; return c.f;
}
__device__ __forceinline__ float t2f(float v){ return v; }
__device__ __forceinline__ float t2f(bf16 v){ return __bfloat162float(v); }

template<typename TIN> struct OutStore;
template<> struct OutStore<float>{
  static __device__ __forceinline__ void st(void* o, size_t i, float v){ ((float*)o)[i] = v; }
};
template<> struct OutStore<bf16>{
  static __device__ __forceinline__ void st(void* o, size_t i, float v){ ((bf16*)o)[i] = __float2bfloat16(v); }
};

// vectorized 4-element load -> float4 (element offset must be %4==0)
template<typename TIN> struct Ld4;
template<> struct Ld4<float>{
  static __device__ __forceinline__ float4 ld(const void* base, size_t eo){
    return *(const float4*)((const float*)base + eo);
  }
};
template<> struct Ld4<bf16>{
  static __device__ __forceinline__ float4 ld(const void* base, size_t eo){
    ushort4 u = *(const ushort4*)((const unsigned short*)base + eo);
    float4 f; f.x = bits2f(u.x); f.y = bits2f(u.y); f.z = bits2f(u.z); f.w = bits2f(u.w);
    return f;
  }
};

template<typename TAB> __device__ __forceinline__ void store4(TAB* p, float a, float b, float c, float d);
template<> __device__ __forceinline__ void store4<float>(float* p, float a, float b, float c, float d){
  float4 v; v.x=a; v.y=b; v.z=c; v.w=d; *(float4*)p = v;
}
template<> __device__ __forceinline__ void store4<bf16>(bf16* p, float a, float b, float c, float d){
  p[0]=__float2bfloat16(a); p[1]=__float2bfloat16(b); p[2]=__float2bfloat16(c); p[3]=__float2bfloat16(d);
}

// ---- dtype detection: f32 data viewed as halfwords has ~0.4% bits[14:7]==0xFF ----
__global__ void detect_kernel(const unsigned short* __restrict__ nd, int* __restrict__ dflag){
  unsigned int i = blockIdx.x * 256u + threadIdx.x;
  unsigned short u = nd[i];
  if (((u >> 7) & 0xFF) == 0xFF) atomicOr(dflag, 1);
}

// ---- qt[c] = bqt[c] + sum_k cos(time_b[k]) * Wqt[k,c] ----
template<typename TIN>
__global__ void qt_kernel(const int* __restrict__ dflag, int want,
                          const void* time_b_v, const void* Wqt_v,
                          const void* bqt_v, float* __restrict__ qt){
  if (*dflag != want) return;
  const TIN* time_b = (const TIN*)time_b_v;
  const TIN* Wqt = (const TIN*)Wqt_v;
  const TIN* bqt = (const TIN*)bqt_v;
  int c = threadIdx.x;
  if (c >= K_DOUT) return;
  float acc = t2f(bqt[c]);
  for (int k = 0; k < K_DT; k++)
    acc += cosf(t2f(time_b[k])) * t2f(Wqt[k * K_DOUT + c]);
  qt[c] = acc;
}

// ---- nodeData @ [Wqn | Wkvn] : 32 rows/block, 8x4 micro-tile, k-chunked LDS ----
// xs stride 68 floats (68 % 32 == 4): staging-write banks = 4(r+g) mod 32,
// spread across all quads (stride 64 put every row in bank 0 -> 1.1e7 conflicts).
// __launch_bounds__(320,8) forces VGPR <= 64 (the 64/128 occupancy cliff):
// acc 32 + w 16 + addr ~= 60, fits. LDS 8.7 KiB -> 6 blocks * 5 waves = 30 waves/CU.
template<typename TAB, typename TIN>
__global__ __launch_bounds__(320, 8)
void node_proj_kernel(const int* __restrict__ dflag, int want,
    const void* nodeData_v, const void* Wqn_v, const void* bqn_v,
    const void* Wkvn_v, const void* bkvn_v,
    TAB* __restrict__ qn_tab, TAB* __restrict__ kvn_tab){
  if (*dflag != want) return;
  __shared__ float xs[32][68];
  int row0 = blockIdx.x * 32;
  int tid = threadIdx.x;
  int ci = tid % 75, ri = tid / 75;     // valid for tid < 300
  const void* W; const TIN* B; int ldw, c0;
  if (ci < 25){ W = Wqn_v;  B = (const TIN*)bqn_v;  ldw = K_DOUT; c0 = 4*ci; }
  else        { W = Wkvn_v; B = (const TIN*)bkvn_v; ldw = K_DKV;  c0 = 4*(ci-25); }
  float acc[8][4] = {};
  #pragma unroll
  for (int c = 0; c < 3; c++){
    const int ng = (c < 2) ? 16 : 11;   // float4-groups this chunk (43 total)
    if (c > 0) __syncthreads();
    for (int idx = tid; idx < 32 * ng; idx += 320){
      int r = idx / ng, g = idx % ng;
      float4 v = Ld4<TIN>::ld(nodeData_v, (size_t)(row0 + r) * K_DN + (16*c + g) * 4);
      *(float4*)&xs[r][g * 4] = v;
    }
    __syncthreads();
    if (tid < 300){
      const float* xbase = &xs[8*ri][0];
      #pragma unroll 1
      for (int g = 0; g < ng; g++){
        int kg = (16*c + g) * 4;
        float4 w0 = Ld4<TIN>::ld(W, (size_t)(kg+0) * ldw + c0);
        float4 w1 = Ld4<TIN>::ld(W, (size_t)(kg+1) * ldw + c0);
        float4 w2 = Ld4<TIN>::ld(W, (size_t)(kg+2) * ldw + c0);
        float4 w3 = Ld4<TIN>::ld(W, (size_t)(kg+3) * ldw + c0);
        #pragma unroll
        for (int i = 0; i < 8; i++){
          float4 a = *(const float4*)(xbase + i * 68 + 4*g);
          acc[i][0] = fmaf(a.x,w0.x, fmaf(a.y,w1.x, fmaf(a.z,w2.x, fmaf(a.w,w3.x, acc[i][0]))));
          acc[i][1] = fmaf(a.x,w0.y, fmaf(a.y,w1.y, fmaf(a.z,w2.y, fmaf(a.w,w3.y, acc[i][1]))));
          acc[i][2] = fmaf(a.x,w0.z, fmaf(a.y,w1.z, fmaf(a.z,w2.z, fmaf(a.w,w3.z, acc[i][2]))));
          acc[i][3] = fmaf(a.x,w0.w, fmaf(a.y,w1.w, fmaf(a.z,w2.w, fmaf(a.w,w3.w, acc[i][3]))));
        }
      }
    }
  }
  if (tid >= 300) return;
  float b0 = t2f(B[c0+0]), b1 = t2f(B[c0+1]), b2 = t2f(B[c0+2]), b3 = t2f(B[c0+3]);
  TAB* tab = (ci < 25) ? qn_tab : kvn_tab;
  #pragma unroll
  for (int i = 0; i < 8; i++){
    size_t row = row0 + 8*ri + i;
    store4<TAB>(&tab[row * ldw + c0], acc[i][0]+b0, acc[i][1]+b1, acc[i][2]+b2, acc[i][3]+b3);
  }
}

// ---- efeat @ Wkve : 40 rows/block, 8x4 micro-tile, k-chunked LDS (10.9 KiB) ----
template<typename TAB, typename TIN>
__global__ __launch_bounds__(256, 8)
void feat_proj_kernel(const int* __restrict__ dflag, int want,
    const void* A_v, const void* W_v, const void* bias_v,
    TAB* __restrict__ out_tab){
  if (*dflag != want) return;
  __shared__ float xs[40][68];
  int row0 = blockIdx.x * 40;
  int tid = threadIdx.x;
  int ci = tid % 50, ri = tid / 50;     // valid for tid < 250
  int c0 = 4 * ci;
  float acc[8][4] = {};
  #pragma unroll
  for (int c = 0; c < 3; c++){
    const int ng = (c < 2) ? 16 : 11;
    if (c > 0) __syncthreads();
    for (int idx = tid; idx < 40 * ng; idx += 256){
      int r = idx / ng, g = idx % ng;
      float4 v = Ld4<TIN>::ld(A_v, (size_t)(row0 + r) * K_DN + (16*c + g) * 4);
      *(float4*)&xs[r][g * 4] = v;
    }
    __syncthreads();
    if (tid < 250){
      const float* xbase = &xs[8*ri][0];
      #pragma unroll 1
      for (int g = 0; g < ng; g++){
        int kg = (16*c + g) * 4;
        float4 w0 = Ld4<TIN>::ld(W_v, (size_t)(kg+0) * K_DKV + c0);
        float4 w1 = Ld4<TIN>::ld(W_v, (size_t)(kg+1) * K_DKV + c0);
        float4 w2 = Ld4<TIN>::ld(W_v, (size_t)(kg+2) * K_DKV + c0);
        float4 w3 = Ld4<TIN>::ld(W_v, (size_t)(kg+3) * K_DKV + c0);
        #pragma unroll
        for (int i = 0; i < 8; i++){
          float4 a = *(const float4*)(xbase + i * 68 + 4*g);
          acc[i][0] = fmaf(a.x,w0.x, fmaf(a.y,w1.x, fmaf(a.z,w2.x, fmaf(a.w,w3.x, acc[i][0]))));
          acc[i][1] = fmaf(a.x,w0.y, fmaf(a.y,w1.y, fmaf(a.z,w2.y, fmaf(a.w,w3.y, acc[i][1]))));
          acc[i][2] = fmaf(a.x,w0.z, fmaf(a.y,w1.z, fmaf(a.z,w2.z, fmaf(a.w,w3.z, acc[i][2]))));
          acc[i][3] = fmaf(a.x,w0.w, fmaf(a.y,w1.w, fmaf(a.z,w2.w, fmaf(a.w,w3.w, acc[i][3]))));
        }
      }
    }
  }
  if (tid >= 250) return;
  const TIN* B = (const TIN*)bias_v;
  float b0 = t2f(B[c0+0]), b1 = t2f(B[c0+1]), b2 = t2f(B[c0+2]), b3 = t2f(B[c0+3]);
  #pragma unroll
  for (int i = 0; i < 8; i++){
    size_t row = row0 + 8*ri + i;
    store4<TAB>(&out_tab[row * K_DKV + c0], acc[i][0]+b0, acc[i][1]+b1, acc[i][2]+b2, acc[i][3]+b3);
  }
}

// ---- cos(t*w+b) @ Wkvt : 40 rows/block, 8x4 micro-tile, k-chunked LDS ----
template<typename TAB, typename TIN>
__global__ __launch_bounds__(256, 8)
void time_proj_kernel(const int* __restrict__ dflag, int want,
    const void* utd_v, const void* time_w_v, const void* time_b_v,
    const void* Wkvt_v, const void* bkvt_v,
    TAB* __restrict__ kvt_tab){
  if (*dflag != want) return;
  __shared__ float xs[40][68];
  __shared__ float ts[40];
  int row0 = blockIdx.x * 40;
  int tid = threadIdx.x;
  if (tid < 40) ts[tid] = t2f(((const TIN*)utd_v)[row0 + tid]);
  __syncthreads();
  int ci = tid % 50, ri = tid / 50;
  int c0 = 4 * ci;
  float acc[8][4] = {};
  #pragma unroll
  for (int c = 0; c < 2; c++){
    const int ng = (c < 1) ? 16 : 9;    // 25 groups total (K=100)
    const int nk = ng * 4;
    if (c > 0) __syncthreads();
    for (int idx = tid; idx < 40 * nk; idx += 256){
      int r = idx / nk, kloc = idx % nk;
      int k = 64*c + kloc;
      xs[r][kloc] = cosf(ts[r] * t2f(((const TIN*)time_w_v)[k]) + t2f(((const TIN*)time_b_v)[k]));
    }
    __syncthreads();
    if (tid < 250){
      const float* xbase = &xs[8*ri][0];
      #pragma unroll 1
      for (int g = 0; g < ng; g++){
        int kg = 64*c + 4*g;
        float4 w0 = Ld4<TIN>::ld(Wkvt_v, (size_t)(kg+0) * K_DKV + c0);
        float4 w1 = Ld4<TIN>::ld(Wkvt_v, (size_t)(kg+1) * K_DKV + c0);
        float4 w2 = Ld4<TIN>::ld(Wkvt_v, (size_t)(kg+2) * K_DKV + c0);
        float4 w3 = Ld4<TIN>::ld(Wkvt_v, (size_t)(kg+3) * K_DKV + c0);
        #pragma unroll
        for (int i = 0; i < 8; i++){
          float4 a = *(const float4*)(xbase + i * 68 + 4*g);
          acc[i][0] = fmaf(a.x,w0.x, fmaf(a.y,w1.x, fmaf(a.z,w2.x, fmaf(a.w,w3.x, acc[i][0]))));
          acc[i][1] = fmaf(a.x,w0.y, fmaf(a.y,w1.y, fmaf(a.z,w2.y, fmaf(a.w,w3.y, acc[i][1]))));
          acc[i][2] = fmaf(a.x,w0.z, fmaf(a.y,w1.z, fmaf(a.z,w2.z, fmaf(a.w,w3.z, acc[i][2]))));
          acc[i][3] = fmaf(a.x,w0.w, fmaf(a.y,w1.w, fmaf(a.z,w2.w, fmaf(a.w,w3.w, acc[i][3]))));
        }
      }
    }
  }
  if (tid >= 250) return;
  const TIN* B = (const TIN*)bkvt_v;
  float b0 = t2f(B[c0+0]), b1 = t2f(B[c0+1]), b2 = t2f(B[c0+2]), b3 = t2f(B[c0+3]);
  #pragma unroll
  for (int i = 0; i < 8; i++){
    size_t row = row0 + 8*ri + i;
    store4<TAB>(&kvt_tab[row * K_DKV + c0], acc[i][0]+b0, acc[i][1]+b1, acc[i][2]+b2, acc[i][3]+b3);
  }
}

// ---- CSR construction ----
__global__ void hist_kernel(const int* __restrict__ dstindex, int* __restrict__ counts){
  int e = blockIdx.x * blockDim.x + threadIdx.x;
  if (e < K_E) atomicAdd(&counts[dstindex[e]], 1);
}

__global__ void scan1_kernel(const int* __restrict__ counts, int* __restrict__ offsets,
                             int* __restrict__ bsum, int n){
  __shared__ int sd[256];
  int b = blockIdx.x, t = threadIdx.x;
  int base = b * 1024 + t * 4;
  int v0=0,v1=0,v2=0,v3=0;
  if (base+0 < n) v0 = counts[base+0];
  if (base+1 < n) v1 = counts[base+1];
  if (base+2 < n) v2 = counts[base+2];
  if (base+3 < n) v3 = counts[base+3];
  int s = v0+v1+v2+v3;
  sd[t] = s;
  __syncthreads();
  for (int off = 1; off < 256; off <<= 1){
    int tmp = (t >= off) ? sd[t-off] : 0;
    __syncthreads();
    sd[t] += tmp;
    __syncthreads();
  }
  int excl = sd[t] - s;
  if (base+0 < n) offsets[base+0] = excl;
  if (base+1 < n) offsets[base+1] = excl + v0;
  if (base+2 < n) offsets[base+2] = excl + v0 + v1;
  if (base+3 < n) offsets[base+3] = excl + v0 + v1 + v2;
  if (t == 255) bsum[b] = sd[255];
}

__global__ void scan2_kernel(int* bsum, int nb){
  if (threadIdx.x == 0 && blockIdx.x == 0){
    int run = 0;
    for (int i = 0; i < nb; i++){ int v = bsum[i]; bsum[i] = run; run += v; }
  }
}

__global__ void scan3_kernel(int* __restrict__ offsets, const int* __restrict__ bsum, int n){
  int i = blockIdx.x * blockDim.x + threadIdx.x;
  if (i < n) offsets[i] += bsum[i >> 10];
}

__global__ void scatter_kernel(const int* __restrict__ dstindex, const int* __restrict__ offsets,
                               int* __restrict__ cursor, int* __restrict__ edge_ids){
  int e = blockIdx.x * blockDim.x + threadIdx.x;
  if (e < K_E){
    int d = dstindex[e];
    int p = atomicAdd(&cursor[d], 1);
    edge_ids[offsets[d] + p] = e;
  }
}

// ---- attention: online softmax, 1 wave per dst (4 dst/block), no LDS/sync ----
template<typename TAB>
__global__ __launch_bounds__(256)
void attn_kernel(
    const int* __restrict__ reverse_nids, const int* __restrict__ reverse_eids,
    const int* __restrict__ reverse_tids,
    const int* __restrict__ dstoff, const int* __restrict__ dstcnt,
    const int* __restrict__ edge_ids,
    const TAB* __restrict__ qn_tab, const TAB* __restrict__ kvn_tab,
    const TAB* __restrict__ kve_tab, const TAB* __restrict__ kvt_tab,
    const float* __restrict__ qt, float* __restrict__ out_agg){
  int tid = threadIdx.x;
  int wave = tid >> 6;
  int l = tid & 63;
  int h = l >> 5;
  int li = l & 31;
  int dst = blockIdx.x * 4 + wave;
  int start = dstoff[dst];
  int cnt = dstcnt[dst];
  int cntw = (cnt + 1 - h) >> 1;    // h=0 gets ceil, h=1 gets floor
  bool act = (li < 25);
  int d4 = 4 * li;
  bool c0h0 = (d4+0) < 50, c1h0 = (d4+1) < 50, c2h0 = (d4+2) < 50, c3h0 = (d4+3) < 50;

  int gn = reverse_nids[dst];
  float4 q = make_float4(0.f,0.f,0.f,0.f);
  if (act){
    float4 qn = Ld4<TAB>::ld(qn_tab, (size_t)gn * K_DOUT + d4);
    float4 qtv = *(const float4*)(qt + d4);
    q.x = qn.x + qtv.x; q.y = qn.y + qtv.y; q.z = qn.z + qtv.z; q.w = qn.w + qtv.w;
  }

  float m0 = -3.0e38f, m1 = -3.0e38f, s0 = 0.f, s1 = 0.f;
  float ax = 0.f, ay = 0.f, az = 0.f, aw = 0.f;   // weighted V accumulator

  for (int j = 0; j < cntw; j++){
    int e   = edge_ids[start + 2*j + h];
    int nid = reverse_nids[K_NUM_DST + e];
    int eid = reverse_eids[e];
    int tde = reverse_tids[e];
    float4 kx = make_float4(0.f,0.f,0.f,0.f);
    if (act){
      float4 k1 = Ld4<TAB>::ld(kvn_tab, (size_t)nid * K_DKV + d4);
      float4 k2 = Ld4<TAB>::ld(kve_tab, (size_t)eid * K_DKV + d4);
      float4 k3 = Ld4<TAB>::ld(kvt_tab, (size_t)tde * K_DKV + d4);
      kx.x = k1.x+k2.x+k3.x; kx.y = k1.y+k2.y+k3.y; kx.z = k1.z+k2.z+k3.z; kx.w = k1.w+k2.w+k3.w;
    }
    float px = q.x*kx.x, py = q.y*kx.y, pz = q.z*kx.z, pw = q.w*kx.w;
    float p0 = (c0h0?px:0.f) + (c1h0?py:0.f) + (c2h0?pz:0.f) + (c3h0?pw:0.f);
    float p1 = (px+py+pz+pw) - p0;
    #pragma unroll
    for (int off = 16; off; off >>= 1){
      p0 += __shfl_xor(p0, off);
      p1 += __shfl_xor(p1, off);
    }
    float a0 = (p0 > 0.f) ? p0 : K_NEG_SLOPE * p0;
    float a1 = (p1 > 0.f) ? p1 : K_NEG_SLOPE * p1;
    float nm0 = fmaxf(m0, a0), nm1 = fmaxf(m1, a1);
    float al0 = __expf(m0 - nm0), al1 = __expf(m1 - nm1);
    float e0  = __expf(a0 - nm0), e1  = __expf(a1 - nm1);
    s0 = s0 * al0 + e0; s1 = s1 * al1 + e1;
    m0 = nm0; m1 = nm1;
    float4 vx = make_float4(0.f,0.f,0.f,0.f);
    if (act){
      float4 v1 = Ld4<TAB>::ld(kvn_tab, (size_t)nid * K_DKV + K_DOUT + d4);
      float4 v2 = Ld4<TAB>::ld(kve_tab, (size_t)eid * K_DKV + K_DOUT + d4);
      float4 v3 = Ld4<TAB>::ld(kvt_tab, (size_t)tde * K_DKV + K_DOUT + d4);
      vx.x = v1.x+v2.x+v3.x; vx.y = v1.y+v2.y+v3.y; vx.z = v1.z+v2.z+v3.z; vx.w = v1.w+v2.w+v3.w;
    }
    ax = ax * (c0h0?al0:al1) + (c0h0?e0:e1) * vx.x;
    ay = ay * (c1h0?al0:al1) + (c1h0?e0:e1) * vx.y;
    az = az * (c2h0?al0:al1) + (c2h0?e0:e1) * vx.z;
    aw = aw * (c3h0?al0:al1) + (c3h0?e0:e1) * vx.w;
  }

  // merge the two halves (flash-attention two-way merge)
  float mo0 = __shfl_xor(m0, 32), so0 = __shfl_xor(s0, 32);
  float mo1 = __shfl_xor(m1, 32), so1 = __shfl_xor(s1, 32);
  float aox = __shfl_xor(ax, 32), aoy = __shfl_xor(ay, 32);
  float aoz = __shfl_xor(az, 32), aow = __shfl_xor(aw, 32);
  float M0 = fmaxf(m0, mo0), M1 = fmaxf(m1, mo1);
  float cs0 = __expf(m0 - M0), co0 = __expf(mo0 - M0);
  float cs1 = __expf(m1 - M1), co1 = __expf(mo1 - M1);
  float S0 = s0 * cs0 + so0 * co0;
  float S1 = s1 * cs1 + so1 * co1;
  float inv0 = (S0 > 0.f) ? 1.f / S0 : 0.f;
  float inv1 = (S1 > 0.f) ? 1.f / S1 : 0.f;
  float rx = c0h0 ? (ax*cs0 + aox*co0)*inv0 : (ax*cs1 + aox*co1)*inv1;
  float ry = c1h0 ? (ay*cs0 + aoy*co0)*inv0 : (ay*cs1 + aoy*co1)*inv1;
  float rz = c2h0 ? (az*cs0 + aoz*co0)*inv0 : (az*cs1 + aoz*co1)*inv1;
  float rw = c3h0 ? (aw*cs0 + aow*co0)*inv0 : (aw*cs1 + aow*co1)*inv1;
  if (h == 0 && act){
    float4 r; r.x=rx; r.y=ry; r.z=rz; r.w=rw;
    *(float4*)(out_agg + (size_t)dst * K_DOUT + d4) = r;
  }
}

// ---- final: relu(concat[out_agg, nodeData[gather]] @ Wout) -> LayerNorm ----
// 32 rows/block, 4x4 micro-tile, row-major k-chunked xs (~16 KB LDS total ->
// 4 blocks/CU). LN stats via LDS partials.
template<typename TIN>
__global__ __launch_bounds__(256)
void final_kernel(const int* __restrict__ dflag, int want,
    const float* __restrict__ out_agg,
    const void* nodeData_v, const int* __restrict__ reverse_nids,
    const void* Wout_v, const void* bout_v,
    const void* ln_g_v, const void* ln_b_v,
    void* out){
  if (*dflag != want) return;
  __shared__ float xs[32][72];
  __shared__ float part[32][25][2];
  __shared__ float stats[32][2];
  __shared__ int gnid[32];
  int dbase = blockIdx.x * 32;
  int tid = threadIdx.x;
  if (tid < 32) gnid[tid] = reverse_nids[dbase + tid];
  __syncthreads();
  int ci = tid % 25, ri = tid / 25;
  int c0 = 4 * ci;
  float acc[4][4] = {};
  #pragma unroll
  for (int c = 0; c < 4; c++){
    if (c > 0) __syncthreads();
    // stage 32 rows x 17 float4-groups; K-range [68c, 68c+68)
    for (int idx = tid; idx < 32 * 17; idx += 256){
      int r = idx / 17, g = idx % 17;
      int gk = (c * 17 + g) * 4;
      float4 v;
      if (gk < 100) v = *(const float4*)(out_agg + (size_t)(dbase + r) * K_DOUT + gk);
      else          v = Ld4<TIN>::ld(nodeData_v, (size_t)gnid[r] * K_DN + (gk - 100));
      *(float4*)&xs[r][g * 4] = v;
    }
    __syncthreads();
    if (tid < 200){
      const float* xbase = &xs[4 * ri][0];
      #pragma unroll 1
      for (int g = 0; g < 17; g++){
        int kg = (c * 17 + g) * 4;
        float4 w0 = Ld4<TIN>::ld(Wout_v, (size_t)(kg+0) * K_DOUT + c0);
        float4 w1 = Ld4<TIN>::ld(Wout_v, (size_t)(kg+1) * K_DOUT + c0);
        float4 w2 = Ld4<TIN>::ld(Wout_v, (size_t)(kg+2) * K_DOUT + c0);
        float4 w3 = Ld4<TIN>::ld(Wout_v, (size_t)(kg+3) * K_DOUT + c0);
        #pragma unroll
        for (int i = 0; i < 4; i++){
          float4 a = *(const float4*)(xbase + i * 72 + 4*g);
          acc[i][0] = fmaf(a.x,w0.x, fmaf(a.y,w1.x, fmaf(a.z,w2.x, fmaf(a.w,w3.x, acc[i][0]))));
          acc[i][1] = fmaf(a.x,w0.y, fmaf(a.y,w1.y, fmaf(a.z,w2.y, fmaf(a.w,w3.y, acc[i][1]))));
          acc[i][2] = fmaf(a.x,w0.z, fmaf(a.y,w1.z, fmaf(a.z,w2.z, fmaf(a.w,w3.z, acc[i][2]))));
          acc[i][3] = fmaf(a.x,w0.w, fmaf(a.y,w1.w, fmaf(a.z,w2.w, fmaf(a.w,w3.w, acc[i][3]))));
        }
      }
    }
  }
  if (tid < 200){
    const TIN* B = (const TIN*)bout_v;
    float b0 = t2f(B[c0+0]), b1 = t2f(B[c0+1]), b2 = t2f(B[c0+2]), b3 = t2f(B[c0+3]);
    #pragma unroll
    for (int i = 0; i < 4; i++){
      acc[i][0] = fmaxf(acc[i][0]+b0, 0.f);
      acc[i][1] = fmaxf(acc[i][1]+b1, 0.f);
      acc[i][2] = fmaxf(acc[i][2]+b2, 0.f);
      acc[i][3] = fmaxf(acc[i][3]+b3, 0.f);
      float s1 = acc[i][0]+acc[i][1]+acc[i][2]+acc[i][3];
      float s2 = acc[i][0]*acc[i][0]+acc[i][1]*acc[i][1]+acc[i][2]*acc[i][2]+acc[i][3]*acc[i][3];
      part[4*ri + i][ci][0] = s1;
      part[4*ri + i][ci][1] = s2;
    }
  }
  __syncthreads();
  if (tid < 32){
    float s1 = 0.f, s2 = 0.f;
    for (int j = 0; j < 25; j++){ s1 += part[tid][j][0]; s2 += part[tid][j][1]; }
    stats[tid][0] = s1; stats[tid][1] = s2;
  }
  __syncthreads();
  if (tid < 200){
    const TIN* G = (const TIN*)ln_g_v; const TIN* Bb = (const TIN*)ln_b_v;
    float g0 = t2f(G[c0+0]), g1 = t2f(G[c0+1]), g2 = t2f(G[c0+2]), g3 = t2f(G[c0+3]);
    float lb0 = t2f(Bb[c0+0]), lb1 = t2f(Bb[c0+1]), lb2 = t2f(Bb[c0+2]), lb3 = t2f(Bb[c0+3]);
    #pragma unroll
    for (int i = 0; i < 4; i++){
      int r = 4*ri + i;
      float mu = stats[r][0] * (1.f / K_DOUT);
      float var = stats[r][1] * (1.f / K_DOUT) - mu * mu;
      float rs = rsqrtf(var + K_LN_EPS);
      size_t o = (size_t)(dbase + r) * K_DOUT + c0;
      OutStore<TIN>::st(out, o+0, (acc[i][0]-mu)*rs*g0 + lb0);
      OutStore<TIN>::st(out, o+1, (acc[i][1]-mu)*rs*g1 + lb1);
      OutStore<TIN>::st(out, o+2, (acc[i][2]-mu)*rs*g2 + lb2);
      OutStore<TIN>::st(out, o+3, (acc[i][3]-mu)*rs*g3 + lb3);
    }
  }
}

// ---- host side ----
static inline size_t al256(size_t b){ return (b + 255) & ~(size_t)255; }

template<typename TAB>
static void run_pipeline(void* const* d_in, void* out, char* ws, hipStream_t stream){
  const void* nodeData = d_in[0];
  const void* efeat    = d_in[1];
  const void* utd      = d_in[2];
  const int* reverse_nids = (const int*)d_in[3];
  const int* reverse_eids = (const int*)d_in[4];
  const int* reverse_tids = (const int*)d_in[5];
  const int* dstindex     = (const int*)d_in[6];
  const void* time_w = d_in[8];
  const void* time_b = d_in[9];
  const void* Wqn  = d_in[10]; const void* bqn  = d_in[11];
  const void* Wqt  = d_in[12]; const void* bqt  = d_in[13];
  const void* Wkvn = d_in[14]; const void* bkvn = d_in[15];
  const void* Wkve = d_in[16]; const void* bkve = d_in[17];
  const void* Wkvt = d_in[18]; const void* bkvt = d_in[19];
  const void* Wout = d_in[20]; const void* bout = d_in[21];
  const void* ln_g = d_in[22]; const void* ln_b = d_in[23];

  char* p = ws;
  int* dflag = (int*)p;       p += 256;
  TAB* qn_tab  = (TAB*)p; p += al256(sizeof(TAB) * (size_t)K_UN * K_DOUT);
  TAB* kvn_tab = (TAB*)p; p += al256(sizeof(TAB) * (size_t)K_UN * K_DKV);
  TAB* kve_tab = (TAB*)p; p += al256(sizeof(TAB) * (size_t)K_UE * K_DKV);
  TAB* kvt_tab = (TAB*)p; p += al256(sizeof(TAB) * (size_t)K_UT * K_DKV);
  float* out_agg = (float*)p; p += al256(sizeof(float) * (size_t)K_NUM_DST * K_DOUT);
  float* qt = (float*)p;      p += al256(sizeof(float) * K_DOUT);
  int* counts = (int*)p;      p += al256(sizeof(int) * K_NUM_DST);
  int* offsets = (int*)p;     p += al256(sizeof(int) * K_NUM_DST);
  int* cursor = (int*)p;      p += al256(sizeof(int) * K_NUM_DST);
  int* bsum = (int*)p;        p += al256(sizeof(int) * 512);
  int* edge_ids = (int*)p;    p += al256(sizeof(int) * (size_t)K_E);

  hipMemsetAsync(dflag, 0, 256, stream);
  hipMemsetAsync(counts, 0, sizeof(int) * K_NUM_DST, stream);
  hipMemsetAsync(cursor, 0, sizeof(int) * K_NUM_DST, stream);

  detect_kernel<<<512, 256, 0, stream>>>((const unsigned short*)nodeData, dflag);

  // f32-input variant (want=1) -- ACTIVE per round-2/3 evidence
  qt_kernel<float><<<1, 128, 0, stream>>>(dflag, 1, time_b, Wqt, bqt, qt);
  node_proj_kernel<TAB, float><<<K_UN / 32, 320, 0, stream>>>(dflag, 1, nodeData, Wqn, bqn, Wkvn, bkvn, qn_tab, kvn_tab);
  feat_proj_kernel<TAB, float><<<K_UE / 40, 256, 0, stream>>>(dflag, 1, efeat, Wkve, bkve, kve_tab);
  time_proj_kernel<TAB, float><<<K_UT / 40, 256, 0, stream>>>(dflag, 1, utd, time_w, time_b, Wkvt, bkvt, kvt_tab);
  // bf16-input variant (want=0) -- insurance, early-exits
  qt_kernel<bf16><<<1, 128, 0, stream>>>(dflag, 0, time_b, Wqt, bqt, qt);
  node_proj_kernel<TAB, bf16><<<K_UN / 32, 320, 0, stream>>>(dflag, 0, nodeData, Wqn, bqn, Wkvn, bkvn, qn_tab, kvn_tab);
  feat_proj_kernel<TAB, bf16><<<K_UE / 40, 256, 0, stream>>>(dflag, 0, efeat, Wkve, bkve, kve_tab);
  time_proj_kernel<TAB, bf16><<<K_UT / 40, 256, 0, stream>>>(dflag, 0, utd, time_w, time_b, Wkvt, bkvt, kvt_tab);

  hist_kernel<<<(K_E + 255) / 256, 256, 0, stream>>>(dstindex, counts);
  int nb = (K_NUM_DST + 1023) / 1024;
  scan1_kernel<<<nb, 256, 0, stream>>>(counts, offsets, bsum, K_NUM_DST);
  scan2_kernel<<<1, 1, 0, stream>>>(bsum, nb);
  scan3_kernel<<<(K_NUM_DST + 255) / 256, 256, 0, stream>>>(offsets, bsum, K_NUM_DST);
  scatter_kernel<<<(K_E + 255) / 256, 256, 0, stream>>>(dstindex, offsets, cursor, edge_ids);

  attn_kernel<TAB><<<K_NUM_DST / 4, 256, 0, stream>>>(reverse_nids, reverse_eids, reverse_tids,
      offsets, counts, edge_ids, qn_tab, kvn_tab, kve_tab, kvt_tab, qt, out_agg);

  final_kernel<float><<<K_NUM_DST / 32, 256, 0, stream>>>(dflag, 1, out_agg, nodeData, reverse_nids,
      Wout, bout, ln_g, ln_b, out);
  final_kernel<bf16><<<K_NUM_DST / 32, 256, 0, stream>>>(dflag, 0, out_agg, nodeData, reverse_nids,
      Wout, bout, ln_g, ln_b, out);
}

extern "C" void kernel_launch(void* const* d_in, const int* in_sizes, int n_in,
                              void* d_out, int out_size, void* d_ws, size_t ws_size,
                              hipStream_t stream){
  (void)in_sizes; (void)n_in; (void)out_size;

  size_t fixed = 256 + al256(4ull * K_NUM_DST * K_DOUT) + al256(4 * K_DOUT)
               + 3 * al256(4 * K_NUM_DST) + al256(4 * 512) + al256(4ull * K_E);
  size_t tab_elems = (size_t)K_UN * K_DOUT + (size_t)K_UN * K_DKV
                   + (size_t)K_UE * K_DKV + (size_t)K_UT * K_DKV;
  size_t need_f32  = fixed + tab_elems * 4 + 8192;
  size_t need_bf16 = fixed + tab_elems * 2 + 8192;

  if (ws_size >= need_f32){
    run_pipeline<float>(d_in, d_out, (char*)d_ws, stream);
  } else if (ws_size >= need_bf16){
    run_pipeline<bf16>(d_in, d_out, (char*)d_ws, stream);
  }
}

// Round 4
// 1737.957 us; speedup vs baseline: 2.7439x; 2.7439x over previous
//
#include <hip/hip_runtime.h>
#include <hip/hip_bf16.h>

typedef __hip_bfloat16 bf16;

// ---- problem constants (fixed by the reference file) ----
#define K_NUM_DST 100000
#define K_E       1000000
#define K_UN      200000
#define K_UE      100000
#define K_UT      100000
#define K_DN      172
#define K_DT      100
#define K_DOUT    100
#define K_DKV     200
#define K_DCAT    272
#define K_NEG_SLOPE 0.2f
#define K_LN_EPS    1e-5f

__device__ __forceinline__ float bits2f(unsigned short u){
  union { float f; unsigned int i; } c; c.i = ((unsigned int)u) << 16; return c.f;
}
__device__ __forceinline__ float t2f(float v){ return v; }
__device__ __forceinline__ float t2f(bf16 v){ return __bfloat162float(v); }

template<typename TIN> struct OutStore;
template<> struct OutStore<float>{
  static __device__ __forceinline__ void st(void* o, size_t i, float v){ ((float*)o)[i] = v; }
};
template<> struct OutStore<bf16>{
  static __device__ __forceinline__ void st(void* o, size_t i, float v){ ((bf16*)o)[i] = __float2bfloat16(v); }
};

// vectorized 4-element load -> float4 (element offset must be %4==0)
template<typename TIN> struct Ld4;
template<> struct Ld4<float>{
  static __device__ __forceinline__ float4 ld(const void* base, size_t eo){
    return *(const float4*)((const float*)base + eo);
  }
};
template<> struct Ld4<bf16>{
  static __device__ __forceinline__ float4 ld(const void* base, size_t eo){
    ushort4 u = *(const ushort4*)((const unsigned short*)base + eo);
    float4 f; f.x = bits2f(u.x); f.y = bits2f(u.y); f.z = bits2f(u.z); f.w = bits2f(u.w);
    return f;
  }
};

template<typename TAB> __device__ __forceinline__ void store4(TAB* p, float a, float b, float c, float d);
template<> __device__ __forceinline__ void store4<float>(float* p, float a, float b, float c, float d){
  float4 v; v.x=a; v.y=b; v.z=c; v.w=d; *(float4*)p = v;
}
template<> __device__ __forceinline__ void store4<bf16>(bf16* p, float a, float b, float c, float d){
  p[0]=__float2bfloat16(a); p[1]=__float2bfloat16(b); p[2]=__float2bfloat16(c); p[3]=__float2bfloat16(d);
}

// ---- dtype detection: f32 data viewed as halfwords has ~0.4% bits[14:7]==0xFF ----
__global__ void detect_kernel(const unsigned short* __restrict__ nd, int* __restrict__ dflag){
  unsigned int i = blockIdx.x * 256u + threadIdx.x;
  unsigned short u = nd[i];
  if (((u >> 7) & 0xFF) == 0xFF) atomicOr(dflag, 1);
}

// ---- qt[c] = bqt[c] + sum_k cos(time_b[k]) * Wqt[k,c] ----
template<typename TIN>
__global__ void qt_kernel(const int* __restrict__ dflag, int want,
                          const void* time_b_v, const void* Wqt_v,
                          const void* bqt_v, float* __restrict__ qt){
  if (*dflag != want) return;
  const TIN* time_b = (const TIN*)time_b_v;
  const TIN* Wqt = (const TIN*)Wqt_v;
  const TIN* bqt = (const TIN*)bqt_v;
  int c = threadIdx.x;
  if (c >= K_DOUT) return;
  float acc = t2f(bqt[c]);
  for (int k = 0; k < K_DT; k++)
    acc += cosf(t2f(time_b[k])) * t2f(Wqt[k * K_DOUT + c]);
  qt[c] = acc;
}

// ---- nodeData @ [Wqn | Wkvn] : 32 rows/block, 8x4 micro-tile, k-chunked LDS ----
// xs stride 68 floats (68 % 32 == 4): staging-write banks spread (verified:
// conflicts 1.09e7 -> 1.75e5 in R2/R3). NO min-waves clamp: R3's (320,8)
// forced a 64-VGPR budget -> acc[8][4]=32 regs alone -> mass spill, 12.3 GB
// scratch HBM traffic. Natural budget ~72-96 VGPR, 4-5 waves/SIMD; R0 vs R1
// showed this kernel is occupancy-insensitive in that range.
template<typename TAB, typename TIN>
__global__ __launch_bounds__(320)
void node_proj_kernel(const int* __restrict__ dflag, int want,
    const void* nodeData_v, const void* Wqn_v, const void* bqn_v,
    const void* Wkvn_v, const void* bkvn_v,
    TAB* __restrict__ qn_tab, TAB* __restrict__ kvn_tab){
  if (*dflag != want) return;
  __shared__ float xs[32][68];
  int row0 = blockIdx.x * 32;
  int tid = threadIdx.x;
  int ci = tid % 75, ri = tid / 75;     // valid for tid < 300
  const void* W; const TIN* B; int ldw, c0;
  if (ci < 25){ W = Wqn_v;  B = (const TIN*)bqn_v;  ldw = K_DOUT; c0 = 4*ci; }
  else        { W = Wkvn_v; B = (const TIN*)bkvn_v; ldw = K_DKV;  c0 = 4*(ci-25); }
  float acc[8][4] = {};
  #pragma unroll
  for (int c = 0; c < 3; c++){
    const int ng = (c < 2) ? 16 : 11;   // float4-groups this chunk (43 total)
    if (c > 0) __syncthreads();
    for (int idx = tid; idx < 32 * ng; idx += 320){
      int r = idx / ng, g = idx % ng;
      float4 v = Ld4<TIN>::ld(nodeData_v, (size_t)(row0 + r) * K_DN + (16*c + g) * 4);
      *(float4*)&xs[r][g * 4] = v;
    }
    __syncthreads();
    if (tid < 300){
      const float* xbase = &xs[8*ri][0];
      #pragma unroll 2
      for (int g = 0; g < ng; g++){
        int kg = (16*c + g) * 4;
        float4 w0 = Ld4<TIN>::ld(W, (size_t)(kg+0) * ldw + c0);
        float4 w1 = Ld4<TIN>::ld(W, (size_t)(kg+1) * ldw + c0);
        float4 w2 = Ld4<TIN>::ld(W, (size_t)(kg+2) * ldw + c0);
        float4 w3 = Ld4<TIN>::ld(W, (size_t)(kg+3) * ldw + c0);
        #pragma unroll
        for (int i = 0; i < 8; i++){
          float4 a = *(const float4*)(xbase + i * 68 + 4*g);
          acc[i][0] = fmaf(a.x,w0.x, fmaf(a.y,w1.x, fmaf(a.z,w2.x, fmaf(a.w,w3.x, acc[i][0]))));
          acc[i][1] = fmaf(a.x,w0.y, fmaf(a.y,w1.y, fmaf(a.z,w2.y, fmaf(a.w,w3.y, acc[i][1]))));
          acc[i][2] = fmaf(a.x,w0.z, fmaf(a.y,w1.z, fmaf(a.z,w2.z, fmaf(a.w,w3.z, acc[i][2]))));
          acc[i][3] = fmaf(a.x,w0.w, fmaf(a.y,w1.w, fmaf(a.z,w2.w, fmaf(a.w,w3.w, acc[i][3]))));
        }
      }
    }
  }
  if (tid >= 300) return;
  float b0 = t2f(B[c0+0]), b1 = t2f(B[c0+1]), b2 = t2f(B[c0+2]), b3 = t2f(B[c0+3]);
  TAB* tab = (ci < 25) ? qn_tab : kvn_tab;
  #pragma unroll
  for (int i = 0; i < 8; i++){
    size_t row = row0 + 8*ri + i;
    store4<TAB>(&tab[row * ldw + c0], acc[i][0]+b0, acc[i][1]+b1, acc[i][2]+b2, acc[i][3]+b3);
  }
}

// ---- efeat @ Wkve : 40 rows/block, 8x4 micro-tile, k-chunked LDS (10.9 KiB) ----
template<typename TAB, typename TIN>
__global__ __launch_bounds__(256)
void feat_proj_kernel(const int* __restrict__ dflag, int want,
    const void* A_v, const void* W_v, const void* bias_v,
    TAB* __restrict__ out_tab){
  if (*dflag != want) return;
  __shared__ float xs[40][68];
  int row0 = blockIdx.x * 40;
  int tid = threadIdx.x;
  int ci = tid % 50, ri = tid / 50;     // valid for tid < 250
  int c0 = 4 * ci;
  float acc[8][4] = {};
  #pragma unroll
  for (int c = 0; c < 3; c++){
    const int ng = (c < 2) ? 16 : 11;
    if (c > 0) __syncthreads();
    for (int idx = tid; idx < 40 * ng; idx += 256){
      int r = idx / ng, g = idx % ng;
      float4 v = Ld4<TIN>::ld(A_v, (size_t)(row0 + r) * K_DN + (16*c + g) * 4);
      *(float4*)&xs[r][g * 4] = v;
    }
    __syncthreads();
    if (tid < 250){
      const float* xbase = &xs[8*ri][0];
      #pragma unroll 2
      for (int g = 0; g < ng; g++){
        int kg = (16*c + g) * 4;
        float4 w0 = Ld4<TIN>::ld(W_v, (size_t)(kg+0) * K_DKV + c0);
        float4 w1 = Ld4<TIN>::ld(W_v, (size_t)(kg+1) * K_DKV + c0);
        float4 w2 = Ld4<TIN>::ld(W_v, (size_t)(kg+2) * K_DKV + c0);
        float4 w3 = Ld4<TIN>::ld(W_v, (size_t)(kg+3) * K_DKV + c0);
        #pragma unroll
        for (int i = 0; i < 8; i++){
          float4 a = *(const float4*)(xbase + i * 68 + 4*g);
          acc[i][0] = fmaf(a.x,w0.x, fmaf(a.y,w1.x, fmaf(a.z,w2.x, fmaf(a.w,w3.x, acc[i][0]))));
          acc[i][1] = fmaf(a.x,w0.y, fmaf(a.y,w1.y, fmaf(a.z,w2.y, fmaf(a.w,w3.y, acc[i][1]))));
          acc[i][2] = fmaf(a.x,w0.z, fmaf(a.y,w1.z, fmaf(a.z,w2.z, fmaf(a.w,w3.z, acc[i][2]))));
          acc[i][3] = fmaf(a.x,w0.w, fmaf(a.y,w1.w, fmaf(a.z,w2.w, fmaf(a.w,w3.w, acc[i][3]))));
        }
      }
    }
  }
  if (tid >= 250) return;
  const TIN* B = (const TIN*)bias_v;
  float b0 = t2f(B[c0+0]), b1 = t2f(B[c0+1]), b2 = t2f(B[c0+2]), b3 = t2f(B[c0+3]);
  #pragma unroll
  for (int i = 0; i < 8; i++){
    size_t row = row0 + 8*ri + i;
    store4<TAB>(&out_tab[row * K_DKV + c0], acc[i][0]+b0, acc[i][1]+b1, acc[i][2]+b2, acc[i][3]+b3);
  }
}

// ---- cos(t*w+b) @ Wkvt : 40 rows/block, 8x4 micro-tile, k-chunked LDS ----
template<typename TAB, typename TIN>
__global__ __launch_bounds__(256)
void time_proj_kernel(const int* __restrict__ dflag, int want,
    const void* utd_v, const void* time_w_v, const void* time_b_v,
    const void* Wkvt_v, const void* bkvt_v,
    TAB* __restrict__ kvt_tab){
  if (*dflag != want) return;
  __shared__ float xs[40][68];
  __shared__ float ts[40];
  int row0 = blockIdx.x * 40;
  int tid = threadIdx.x;
  if (tid < 40) ts[tid] = t2f(((const TIN*)utd_v)[row0 + tid]);
  __syncthreads();
  int ci = tid % 50, ri = tid / 50;
  int c0 = 4 * ci;
  float acc[8][4] = {};
  #pragma unroll
  for (int c = 0; c < 2; c++){
    const int ng = (c < 1) ? 16 : 9;    // 25 groups total (K=100)
    const int nk = ng * 4;
    if (c > 0) __syncthreads();
    for (int idx = tid; idx < 40 * nk; idx += 256){
      int r = idx / nk, kloc = idx % nk;
      int k = 64*c + kloc;
      xs[r][kloc] = cosf(ts[r] * t2f(((const TIN*)time_w_v)[k]) + t2f(((const TIN*)time_b_v)[k]));
    }
    __syncthreads();
    if (tid < 250){
      const float* xbase = &xs[8*ri][0];
      #pragma unroll 2
      for (int g = 0; g < ng; g++){
        int kg = 64*c + 4*g;
        float4 w0 = Ld4<TIN>::ld(Wkvt_v, (size_t)(kg+0) * K_DKV + c0);
        float4 w1 = Ld4<TIN>::ld(Wkvt_v, (size_t)(kg+1) * K_DKV + c0);
        float4 w2 = Ld4<TIN>::ld(Wkvt_v, (size_t)(kg+2) * K_DKV + c0);
        float4 w3 = Ld4<TIN>::ld(Wkvt_v, (size_t)(kg+3) * K_DKV + c0);
        #pragma unroll
        for (int i = 0; i < 8; i++){
          float4 a = *(const float4*)(xbase + i * 68 + 4*g);
          acc[i][0] = fmaf(a.x,w0.x, fmaf(a.y,w1.x, fmaf(a.z,w2.x, fmaf(a.w,w3.x, acc[i][0]))));
          acc[i][1] = fmaf(a.x,w0.y, fmaf(a.y,w1.y, fmaf(a.z,w2.y, fmaf(a.w,w3.y, acc[i][1]))));
          acc[i][2] = fmaf(a.x,w0.z, fmaf(a.y,w1.z, fmaf(a.z,w2.z, fmaf(a.w,w3.z, acc[i][2]))));
          acc[i][3] = fmaf(a.x,w0.w, fmaf(a.y,w1.w, fmaf(a.z,w2.w, fmaf(a.w,w3.w, acc[i][3]))));
        }
      }
    }
  }
  if (tid >= 250) return;
  const TIN* B = (const TIN*)bkvt_v;
  float b0 = t2f(B[c0+0]), b1 = t2f(B[c0+1]), b2 = t2f(B[c0+2]), b3 = t2f(B[c0+3]);
  #pragma unroll
  for (int i = 0; i < 8; i++){
    size_t row = row0 + 8*ri + i;
    store4<TAB>(&kvt_tab[row * K_DKV + c0], acc[i][0]+b0, acc[i][1]+b1, acc[i][2]+b2, acc[i][3]+b3);
  }
}

// ---- CSR construction ----
__global__ void hist_kernel(const int* __restrict__ dstindex, int* __restrict__ counts){
  int e = blockIdx.x * blockDim.x + threadIdx.x;
  if (e < K_E) atomicAdd(&counts[dstindex[e]], 1);
}

__global__ void scan1_kernel(const int* __restrict__ counts, int* __restrict__ offsets,
                             int* __restrict__ bsum, int n){
  __shared__ int sd[256];
  int b = blockIdx.x, t = threadIdx.x;
  int base = b * 1024 + t * 4;
  int v0=0,v1=0,v2=0,v3=0;
  if (base+0 < n) v0 = counts[base+0];
  if (base+1 < n) v1 = counts[base+1];
  if (base+2 < n) v2 = counts[base+2];
  if (base+3 < n) v3 = counts[base+3];
  int s = v0+v1+v2+v3;
  sd[t] = s;
  __syncthreads();
  for (int off = 1; off < 256; off <<= 1){
    int tmp = (t >= off) ? sd[t-off] : 0;
    __syncthreads();
    sd[t] += tmp;
    __syncthreads();
  }
  int excl = sd[t] - s;
  if (base+0 < n) offsets[base+0] = excl;
  if (base+1 < n) offsets[base+1] = excl + v0;
  if (base+2 < n) offsets[base+2] = excl + v0 + v1;
  if (base+3 < n) offsets[base+3] = excl + v0 + v1 + v2;
  if (t == 255) bsum[b] = sd[255];
}

__global__ void scan2_kernel(int* bsum, int nb){
  if (threadIdx.x == 0 && blockIdx.x == 0){
    int run = 0;
    for (int i = 0; i < nb; i++){ int v = bsum[i]; bsum[i] = run; run += v; }
  }
}

__global__ void scan3_kernel(int* __restrict__ offsets, const int* __restrict__ bsum, int n){
  int i = blockIdx.x * blockDim.x + threadIdx.x;
  if (i < n) offsets[i] += bsum[i >> 10];
}

__global__ void scatter_kernel(const int* __restrict__ dstindex, const int* __restrict__ offsets,
                               int* __restrict__ cursor, int* __restrict__ edge_ids){
  int e = blockIdx.x * blockDim.x + threadIdx.x;
  if (e < K_E){
    int d = dstindex[e];
    int p = atomicAdd(&cursor[d], 1);
    edge_ids[offsets[d] + p] = e;
  }
}

// ---- attention: online softmax, 1 wave per dst (4 dst/block), no LDS/sync ----
template<typename TAB>
__global__ __launch_bounds__(256)
void attn_kernel(
    const int* __restrict__ reverse_nids, const int* __restrict__ reverse_eids,
    const int* __restrict__ reverse_tids,
    const int* __restrict__ dstoff, const int* __restrict__ dstcnt,
    const int* __restrict__ edge_ids,
    const TAB* __restrict__ qn_tab, const TAB* __restrict__ kvn_tab,
    const TAB* __restrict__ kve_tab, const TAB* __restrict__ kvt_tab,
    const float* __restrict__ qt, float* __restrict__ out_agg){
  int tid = threadIdx.x;
  int wave = tid >> 6;
  int l = tid & 63;
  int h = l >> 5;
  int li = l & 31;
  int dst = blockIdx.x * 4 + wave;
  int start = dstoff[dst];
  int cnt = dstcnt[dst];
  int cntw = (cnt + 1 - h) >> 1;    // h=0 gets ceil, h=1 gets floor
  bool act = (li < 25);
  int d4 = 4 * li;
  bool c0h0 = (d4+0) < 50, c1h0 = (d4+1) < 50, c2h0 = (d4+2) < 50, c3h0 = (d4+3) < 50;

  int gn = reverse_nids[dst];
  float4 q = make_float4(0.f,0.f,0.f,0.f);
  if (act){
    float4 qn = Ld4<TAB>::ld(qn_tab, (size_t)gn * K_DOUT + d4);
    float4 qtv = *(const float4*)(qt + d4);
    q.x = qn.x + qtv.x; q.y = qn.y + qtv.y; q.z = qn.z + qtv.z; q.w = qn.w + qtv.w;
  }

  float m0 = -3.0e38f, m1 = -3.0e38f, s0 = 0.f, s1 = 0.f;
  float ax = 0.f, ay = 0.f, az = 0.f, aw = 0.f;   // weighted V accumulator

  for (int j = 0; j < cntw; j++){
    int e   = edge_ids[start + 2*j + h];
    int nid = reverse_nids[K_NUM_DST + e];
    int eid = reverse_eids[e];
    int tde = reverse_tids[e];
    float4 kx = make_float4(0.f,0.f,0.f,0.f);
    if (act){
      float4 k1 = Ld4<TAB>::ld(kvn_tab, (size_t)nid * K_DKV + d4);
      float4 k2 = Ld4<TAB>::ld(kve_tab, (size_t)eid * K_DKV + d4);
      float4 k3 = Ld4<TAB>::ld(kvt_tab, (size_t)tde * K_DKV + d4);
      kx.x = k1.x+k2.x+k3.x; kx.y = k1.y+k2.y+k3.y; kx.z = k1.z+k2.z+k3.z; kx.w = k1.w+k2.w+k3.w;
    }
    float px = q.x*kx.x, py = q.y*kx.y, pz = q.z*kx.z, pw = q.w*kx.w;
    float p0 = (c0h0?px:0.f) + (c1h0?py:0.f) + (c2h0?pz:0.f) + (c3h0?pw:0.f);
    float p1 = (px+py+pz+pw) - p0;
    #pragma unroll
    for (int off = 16; off; off >>= 1){
      p0 += __shfl_xor(p0, off);
      p1 += __shfl_xor(p1, off);
    }
    float a0 = (p0 > 0.f) ? p0 : K_NEG_SLOPE * p0;
    float a1 = (p1 > 0.f) ? p1 : K_NEG_SLOPE * p1;
    float nm0 = fmaxf(m0, a0), nm1 = fmaxf(m1, a1);
    float al0 = __expf(m0 - nm0), al1 = __expf(m1 - nm1);
    float e0  = __expf(a0 - nm0), e1  = __expf(a1 - nm1);
    s0 = s0 * al0 + e0; s1 = s1 * al1 + e1;
    m0 = nm0; m1 = nm1;
    float4 vx = make_float4(0.f,0.f,0.f,0.f);
    if (act){
      float4 v1 = Ld4<TAB>::ld(kvn_tab, (size_t)nid * K_DKV + K_DOUT + d4);
      float4 v2 = Ld4<TAB>::ld(kve_tab, (size_t)eid * K_DKV + K_DOUT + d4);
      float4 v3 = Ld4<TAB>::ld(kvt_tab, (size_t)tde * K_DKV + K_DOUT + d4);
      vx.x = v1.x+v2.x+v3.x; vx.y = v1.y+v2.y+v3.y; vx.z = v1.z+v2.z+v3.z; vx.w = v1.w+v2.w+v3.w;
    }
    ax = ax * (c0h0?al0:al1) + (c0h0?e0:e1) * vx.x;
    ay = ay * (c1h0?al0:al1) + (c1h0?e0:e1) * vx.y;
    az = az * (c2h0?al0:al1) + (c2h0?e0:e1) * vx.z;
    aw = aw * (c3h0?al0:al1) + (c3h0?e0:e1) * vx.w;
  }

  // merge the two halves (flash-attention two-way merge)
  float mo0 = __shfl_xor(m0, 32), so0 = __shfl_xor(s0, 32);
  float mo1 = __shfl_xor(m1, 32), so1 = __shfl_xor(s1, 32);
  float aox = __shfl_xor(ax, 32), aoy = __shfl_xor(ay, 32);
  float aoz = __shfl_xor(az, 32), aow = __shfl_xor(aw, 32);
  float M0 = fmaxf(m0, mo0), M1 = fmaxf(m1, mo1);
  float cs0 = __expf(m0 - M0), co0 = __expf(mo0 - M0);
  float cs1 = __expf(m1 - M1), co1 = __expf(mo1 - M1);
  float S0 = s0 * cs0 + so0 * co0;
  float S1 = s1 * cs1 + so1 * co1;
  float inv0 = (S0 > 0.f) ? 1.f / S0 : 0.f;
  float inv1 = (S1 > 0.f) ? 1.f / S1 : 0.f;
  float rx = c0h0 ? (ax*cs0 + aox*co0)*inv0 : (ax*cs1 + aox*co1)*inv1;
  float ry = c1h0 ? (ay*cs0 + aoy*co0)*inv0 : (ay*cs1 + aoy*co1)*inv1;
  float rz = c2h0 ? (az*cs0 + aoz*co0)*inv0 : (az*cs1 + aoz*co1)*inv1;
  float rw = c3h0 ? (aw*cs0 + aow*co0)*inv0 : (aw*cs1 + aow*co1)*inv1;
  if (h == 0 && act){
    float4 r; r.x=rx; r.y=ry; r.z=rz; r.w=rw;
    *(float4*)(out_agg + (size_t)dst * K_DOUT + d4) = r;
  }
}

// ---- final: relu(concat[out_agg, nodeData[gather]] @ Wout) -> LayerNorm ----
// 32 rows/block, 4x4 micro-tile, row-major k-chunked xs (~16 KB LDS total ->
// 4 blocks/CU). LN stats via LDS partials.
template<typename TIN>
__global__ __launch_bounds__(256)
void final_kernel(const int* __restrict__ dflag, int want,
    const float* __restrict__ out_agg,
    const void* nodeData_v, const int* __restrict__ reverse_nids,
    const void* Wout_v, const void* bout_v,
    const void* ln_g_v, const void* ln_b_v,
    void* out){
  if (*dflag != want) return;
  __shared__ float xs[32][72];
  __shared__ float part[32][25][2];
  __shared__ float stats[32][2];
  __shared__ int gnid[32];
  int dbase = blockIdx.x * 32;
  int tid = threadIdx.x;
  if (tid < 32) gnid[tid] = reverse_nids[dbase + tid];
  __syncthreads();
  int ci = tid % 25, ri = tid / 25;
  int c0 = 4 * ci;
  float acc[4][4] = {};
  #pragma unroll
  for (int c = 0; c < 4; c++){
    if (c > 0) __syncthreads();
    // stage 32 rows x 17 float4-groups; K-range [68c, 68c+68)
    for (int idx = tid; idx < 32 * 17; idx += 256){
      int r = idx / 17, g = idx % 17;
      int gk = (c * 17 + g) * 4;
      float4 v;
      if (gk < 100) v = *(const float4*)(out_agg + (size_t)(dbase + r) * K_DOUT + gk);
      else          v = Ld4<TIN>::ld(nodeData_v, (size_t)gnid[r] * K_DN + (gk - 100));
      *(float4*)&xs[r][g * 4] = v;
    }
    __syncthreads();
    if (tid < 200){
      const float* xbase = &xs[4 * ri][0];
      #pragma unroll 2
      for (int g = 0; g < 17; g++){
        int kg = (c * 17 + g) * 4;
        float4 w0 = Ld4<TIN>::ld(Wout_v, (size_t)(kg+0) * K_DOUT + c0);
        float4 w1 = Ld4<TIN>::ld(Wout_v, (size_t)(kg+1) * K_DOUT + c0);
        float4 w2 = Ld4<TIN>::ld(Wout_v, (size_t)(kg+2) * K_DOUT + c0);
        float4 w3 = Ld4<TIN>::ld(Wout_v, (size_t)(kg+3) * K_DOUT + c0);
        #pragma unroll
        for (int i = 0; i < 4; i++){
          float4 a = *(const float4*)(xbase + i * 72 + 4*g);
          acc[i][0] = fmaf(a.x,w0.x, fmaf(a.y,w1.x, fmaf(a.z,w2.x, fmaf(a.w,w3.x, acc[i][0]))));
          acc[i][1] = fmaf(a.x,w0.y, fmaf(a.y,w1.y, fmaf(a.z,w2.y, fmaf(a.w,w3.y, acc[i][1]))));
          acc[i][2] = fmaf(a.x,w0.z, fmaf(a.y,w1.z, fmaf(a.z,w2.z, fmaf(a.w,w3.z, acc[i][2]))));
          acc[i][3] = fmaf(a.x,w0.w, fmaf(a.y,w1.w, fmaf(a.z,w2.w, fmaf(a.w,w3.w, acc[i][3]))));
        }
      }
    }
  }
  if (tid < 200){
    const TIN* B = (const TIN*)bout_v;
    float b0 = t2f(B[c0+0]), b1 = t2f(B[c0+1]), b2 = t2f(B[c0+2]), b3 = t2f(B[c0+3]);
    #pragma unroll
    for (int i = 0; i < 4; i++){
      acc[i][0] = fmaxf(acc[i][0]+b0, 0.f);
      acc[i][1] = fmaxf(acc[i][1]+b1, 0.f);
      acc[i][2] = fmaxf(acc[i][2]+b2, 0.f);
      acc[i][3] = fmaxf(acc[i][3]+b3, 0.f);
      float s1 = acc[i][0]+acc[i][1]+acc[i][2]+acc[i][3];
      float s2 = acc[i][0]*acc[i][0]+acc[i][1]*acc[i][1]+acc[i][2]*acc[i][2]+acc[i][3]*acc[i][3];
      part[4*ri + i][ci][0] = s1;
      part[4*ri + i][ci][1] = s2;
    }
  }
  __syncthreads();
  if (tid < 32){
    float s1 = 0.f, s2 = 0.f;
    for (int j = 0; j < 25; j++){ s1 += part[tid][j][0]; s2 += part[tid][j][1]; }
    stats[tid][0] = s1; stats[tid][1] = s2;
  }
  __syncthreads();
  if (tid < 200){
    const TIN* G = (const TIN*)ln_g_v; const TIN* Bb = (const TIN*)ln_b_v;
    float g0 = t2f(G[c0+0]), g1 = t2f(G[c0+1]), g2 = t2f(G[c0+2]), g3 = t2f(G[c0+3]);
    float lb0 = t2f(Bb[c0+0]), lb1 = t2f(Bb[c0+1]), lb2 = t2f(Bb[c0+2]), lb3 = t2f(Bb[c0+3]);
    #pragma unroll
    for (int i = 0; i < 4; i++){
      int r = 4*ri + i;
      float mu = stats[r][0] * (1.f / K_DOUT);
      float var = stats[r][1] * (1.f / K_DOUT) - mu * mu;
      float rs = rsqrtf(var + K_LN_EPS);
      size_t o = (size_t)(dbase + r) * K_DOUT + c0;
      OutStore<TIN>::st(out, o+0, (acc[i][0]-mu)*rs*g0 + lb0);
      OutStore<TIN>::st(out, o+1, (acc[i][1]-mu)*rs*g1 + lb1);
      OutStore<TIN>::st(out, o+2, (acc[i][2]-mu)*rs*g2 + lb2);
      OutStore<TIN>::st(out, o+3, (acc[i][3]-mu)*rs*g3 + lb3);
    }
  }
}

// ---- host side ----
static inline size_t al256(size_t b){ return (b + 255) & ~(size_t)255; }

template<typename TAB>
static void run_pipeline(void* const* d_in, void* out, char* ws, hipStream_t stream){
  const void* nodeData = d_in[0];
  const void* efeat    = d_in[1];
  const void* utd      = d_in[2];
  const int* reverse_nids = (const int*)d_in[3];
  const int* reverse_eids = (const int*)d_in[4];
  const int* reverse_tids = (const int*)d_in[5];
  const int* dstindex     = (const int*)d_in[6];
  const void* time_w = d_in[8];
  const void* time_b = d_in[9];
  const void* Wqn  = d_in[10]; const void* bqn  = d_in[11];
  const void* Wqt  = d_in[12]; const void* bqt  = d_in[13];
  const void* Wkvn = d_in[14]; const void* bkvn = d_in[15];
  const void* Wkve = d_in[16]; const void* bkve = d_in[17];
  const void* Wkvt = d_in[18]; const void* bkvt = d_in[19];
  const void* Wout = d_in[20]; const void* bout = d_in[21];
  const void* ln_g = d_in[22]; const void* ln_b = d_in[23];

  char* p = ws;
  int* dflag = (int*)p;       p += 256;
  TAB* qn_tab  = (TAB*)p; p += al256(sizeof(TAB) * (size_t)K_UN * K_DOUT);
  TAB* kvn_tab = (TAB*)p; p += al256(sizeof(TAB) * (size_t)K_UN * K_DKV);
  TAB* kve_tab = (TAB*)p; p += al256(sizeof(TAB) * (size_t)K_UE * K_DKV);
  TAB* kvt_tab = (TAB*)p; p += al256(sizeof(TAB) * (size_t)K_UT * K_DKV);
  float* out_agg = (float*)p; p += al256(sizeof(float) * (size_t)K_NUM_DST * K_DOUT);
  float* qt = (float*)p;      p += al256(sizeof(float) * K_DOUT);
  int* counts = (int*)p;      p += al256(sizeof(int) * K_NUM_DST);
  int* offsets = (int*)p;     p += al256(sizeof(int) * K_NUM_DST);
  int* cursor = (int*)p;      p += al256(sizeof(int) * K_NUM_DST);
  int* bsum = (int*)p;        p += al256(sizeof(int) * 512);
  int* edge_ids = (int*)p;    p += al256(sizeof(int) * (size_t)K_E);

  hipMemsetAsync(dflag, 0, 256, stream);
  hipMemsetAsync(counts, 0, sizeof(int) * K_NUM_DST, stream);
  hipMemsetAsync(cursor, 0, sizeof(int) * K_NUM_DST, stream);

  detect_kernel<<<512, 256, 0, stream>>>((const unsigned short*)nodeData, dflag);

  // f32-input variant (want=1) -- ACTIVE per round-2/3 evidence
  qt_kernel<float><<<1, 128, 0, stream>>>(dflag, 1, time_b, Wqt, bqt, qt);
  node_proj_kernel<TAB, float><<<K_UN / 32, 320, 0, stream>>>(dflag, 1, nodeData, Wqn, bqn, Wkvn, bkvn, qn_tab, kvn_tab);
  feat_proj_kernel<TAB, float><<<K_UE / 40, 256, 0, stream>>>(dflag, 1, efeat, Wkve, bkve, kve_tab);
  time_proj_kernel<TAB, float><<<K_UT / 40, 256, 0, stream>>>(dflag, 1, utd, time_w, time_b, Wkvt, bkvt, kvt_tab);
  // bf16-input variant (want=0) -- insurance, early-exits
  qt_kernel<bf16><<<1, 128, 0, stream>>>(dflag, 0, time_b, Wqt, bqt, qt);
  node_proj_kernel<TAB, bf16><<<K_UN / 32, 320, 0, stream>>>(dflag, 0, nodeData, Wqn, bqn, Wkvn, bkvn, qn_tab, kvn_tab);
  feat_proj_kernel<TAB, bf16><<<K_UE / 40, 256, 0, stream>>>(dflag, 0, efeat, Wkve, bkve, kve_tab);
  time_proj_kernel<TAB, bf16><<<K_UT / 40, 256, 0, stream>>>(dflag, 0, utd, time_w, time_b, Wkvt, bkvt, kvt_tab);

  hist_kernel<<<(K_E + 255) / 256, 256, 0, stream>>>(dstindex, counts);
  int nb = (K_NUM_DST + 1023) / 1024;
  scan1_kernel<<<nb, 256, 0, stream>>>(counts, offsets, bsum, K_NUM_DST);
  scan2_kernel<<<1, 1, 0, stream>>>(bsum, nb);
  scan3_kernel<<<(K_NUM_DST + 255) / 256, 256, 0, stream>>>(offsets, bsum, K_NUM_DST);
  scatter_kernel<<<(K_E + 255) / 256, 256, 0, stream>>>(dstindex, offsets, cursor, edge_ids);

  attn_kernel<TAB><<<K_NUM_DST / 4, 256, 0, stream>>>(reverse_nids, reverse_eids, reverse_tids,
      offsets, counts, edge_ids, qn_tab, kvn_tab, kve_tab, kvt_tab, qt, out_agg);

  final_kernel<float><<<K_NUM_DST / 32, 256, 0, stream>>>(dflag, 1, out_agg, nodeData, reverse_nids,
      Wout, bout, ln_g, ln_b, out);
  final_kernel<bf16><<<K_NUM_DST / 32, 256, 0, stream>>>(dflag, 0, out_agg, nodeData, reverse_nids,
      Wout, bout, ln_g, ln_b, out);
}

extern "C" void kernel_launch(void* const* d_in, const int* in_sizes, int n_in,
                              void* d_out, int out_size, void* d_ws, size_t ws_size,
                              hipStream_t stream){
  (void)in_sizes; (void)n_in; (void)out_size;

  size_t fixed = 256 + al256(4ull * K_NUM_DST * K_DOUT) + al256(4 * K_DOUT)
               + 3 * al256(4 * K_NUM_DST) + al256(4 * 512) + al256(4ull * K_E);
  size_t tab_elems = (size_t)K_UN * K_DOUT + (size_t)K_UN * K_DKV
                   + (size_t)K_UE * K_DKV + (size_t)K_UT * K_DKV;
  size_t need_f32  = fixed + tab_elems * 4 + 8192;
  size_t need_bf16 = fixed + tab_elems * 2 + 8192;

  if (ws_size >= need_f32){
    run_pipeline<float>(d_in, d_out, (char*)d_ws, stream);
  } else if (ws_size >= need_bf16){
    run_pipeline<bf16>(d_in, d_out, (char*)d_ws, stream);
  }
}

// Round 5
// 1737.273 us; speedup vs baseline: 2.7450x; 1.0004x over previous
//
#include <hip/hip_runtime.h>
#include <hip/hip_bf16.h>

typedef __hip_bfloat16 bf16;
typedef unsigned short u16;
typedef __attribute__((ext_vector_type(8))) short bf16x8s;   // 8 bf16 = 4 VGPRs
typedef __attribute__((ext_vector_type(4))) float f32x4;

// ---- problem constants (fixed by the reference file) ----
#define K_NUM_DST 100000
#define K_E       1000000
#define K_UN      200000
#define K_UE      100000
#define K_UT      100000
#define K_DN      172
#define K_DT      100
#define K_DOUT    100
#define K_DKV     200
#define K_DCAT    272
#define K_NEG_SLOPE 0.2f
#define K_LN_EPS    1e-5f

// packed-B fragment table geometry (MFMA path)
#define NT_NODE 19   // ceil(304/16): cols 0..99 qn, 100..299 kvn, 300..303 pad
#define NS_NODE 6    // K=172 padded to 192, 6 steps of 32
#define NT_KV   13   // ceil(208/16): cols 0..199, 200..207 pad
#define NS_KVE  6
#define NS_KVT  4    // K=100 padded to 128

__device__ __forceinline__ float bits2f(u16 u){
  union { float f; unsigned int i; } c; c.i = ((unsigned int)u) << 16; return c.f;
}
__device__ __forceinline__ u16 f2bfbits(float f){
  bf16 h = __float2bfloat16(f);
  return *(u16*)&h;
}
__device__ __forceinline__ unsigned int pk2(float a, float b){
  return (unsigned int)f2bfbits(a) | ((unsigned int)f2bfbits(b) << 16);
}
__device__ __forceinline__ float t2f(float v){ return v; }
__device__ __forceinline__ float t2f(bf16 v){ return __bfloat162float(v); }

template<typename TIN> struct OutStore;
template<> struct OutStore<float>{
  static __device__ __forceinline__ void st(void* o, size_t i, float v){ ((float*)o)[i] = v; }
};
template<> struct OutStore<bf16>{
  static __device__ __forceinline__ void st(void* o, size_t i, float v){ ((bf16*)o)[i] = __float2bfloat16(v); }
};

// vectorized 4-element load -> float4 (element offset must be %4==0)
template<typename TIN> struct Ld4;
template<> struct Ld4<float>{
  static __device__ __forceinline__ float4 ld(const void* base, size_t eo){
    return *(const float4*)((const float*)base + eo);
  }
};
template<> struct Ld4<bf16>{
  static __device__ __forceinline__ float4 ld(const void* base, size_t eo){
    ushort4 u = *(const ushort4*)((const u16*)base + eo);
    float4 f; f.x = bits2f(u.x); f.y = bits2f(u.y); f.z = bits2f(u.z); f.w = bits2f(u.w);
    return f;
  }
};

template<typename TAB> __device__ __forceinline__ void store4(TAB* p, float a, float b, float c, float d);
template<> __device__ __forceinline__ void store4<float>(float* p, float a, float b, float c, float d){
  float4 v; v.x=a; v.y=b; v.z=c; v.w=d; *(float4*)p = v;
}
template<> __device__ __forceinline__ void store4<bf16>(bf16* p, float a, float b, float c, float d){
  p[0]=__float2bfloat16(a); p[1]=__float2bfloat16(b); p[2]=__float2bfloat16(c); p[3]=__float2bfloat16(d);
}

// ---- dtype detection: f32 data viewed as halfwords has ~0.4% bits[14:7]==0xFF ----
// (bench evidence R0-R4: FETCH_SIZE 68MB = bf16 nodeData -> ACTIVE path is want=0 / bf16 inputs)
__global__ void detect_kernel(const u16* __restrict__ nd, int* __restrict__ dflag){
  unsigned int i = blockIdx.x * 256u + threadIdx.x;
  u16 u = nd[i];
  if (((u >> 7) & 0xFF) == 0xFF) atomicOr(dflag, 1);
}

// ---- qt[c] = bqt[c] + sum_k cos(time_b[k]) * Wqt[k,c] ----
template<typename TIN>
__global__ void qt_kernel(const int* __restrict__ dflag, int want,
                          const void* time_b_v, const void* Wqt_v,
                          const void* bqt_v, float* __restrict__ qt){
  if (*dflag != want) return;
  const TIN* time_b = (const TIN*)time_b_v;
  const TIN* Wqt = (const TIN*)Wqt_v;
  const TIN* bqt = (const TIN*)bqt_v;
  int c = threadIdx.x;
  if (c >= K_DOUT) return;
  float acc = t2f(bqt[c]);
  for (int k = 0; k < K_DT; k++)
    acc += cosf(t2f(time_b[k])) * t2f(Wqt[k * K_DOUT + c]);
  qt[c] = acc;
}

// ============================================================================
// bf16-input path: MFMA projections.
// Inputs AND weights are bf16 -> mfma bf16xbf16->f32 products are EXACT;
// only f32 accumulation order differs from the old VALU path.
// B packed per (col-tile c, k-step s): Bp[((c*NS+s)*64 + lane)*8 + e] =
//   W[k = s*32 + (lane>>4)*8 + e][col = c*16 + (lane&15)]   (0 outside K/N)
// A frag: row = lane&15, k = (lane>>4)*8 + e (contiguous-8, fp8-x32 convention)
// D frag: col = lane&15, row = 4*(lane>>4) + reg  [m89-verified]
// ============================================================================

__global__ void pack_node_w_kernel(const int* __restrict__ dflag,
    const u16* __restrict__ Wqn, const u16* __restrict__ Wkvn, u16* __restrict__ Bp){
  if (*dflag != 0) return;
  int t = blockIdx.x * 256 + threadIdx.x;
  if (t >= NT_NODE * NS_NODE * 64) return;
  int lane = t & 63; int cs = t >> 6; int s = cs % NS_NODE, c = cs / NS_NODE;
  int col = c * 16 + (lane & 15);
  int k0 = s * 32 + (lane >> 4) * 8;
  u16 v[8];
  #pragma unroll
  for (int e = 0; e < 8; e++){
    int k = k0 + e; u16 x = 0;
    if (k < K_DN){
      if (col < K_DOUT) x = Wqn[(size_t)k * K_DOUT + col];
      else if (col < K_DOUT + K_DKV) x = Wkvn[(size_t)k * K_DKV + (col - K_DOUT)];
    }
    v[e] = x;
  }
  uint4 o;
  o.x = (unsigned)v[0] | ((unsigned)v[1] << 16);
  o.y = (unsigned)v[2] | ((unsigned)v[3] << 16);
  o.z = (unsigned)v[4] | ((unsigned)v[5] << 16);
  o.w = (unsigned)v[6] | ((unsigned)v[7] << 16);
  *(uint4*)&Bp[(size_t)t * 8] = o;
}

__global__ void pack_w_kernel(const int* __restrict__ dflag,
    const u16* __restrict__ W, int K, int N, int NT, int NS, u16* __restrict__ Bp){
  if (*dflag != 0) return;
  int t = blockIdx.x * 256 + threadIdx.x;
  if (t >= NT * NS * 64) return;
  int lane = t & 63; int cs = t >> 6; int s = cs % NS, c = cs / NS;
  int col = c * 16 + (lane & 15);
  int k0 = s * 32 + (lane >> 4) * 8;
  u16 v[8];
  #pragma unroll
  for (int e = 0; e < 8; e++){
    int k = k0 + e;
    v[e] = (k < K && col < N) ? W[(size_t)k * N + col] : (u16)0;
  }
  uint4 o;
  o.x = (unsigned)v[0] | ((unsigned)v[1] << 16);
  o.y = (unsigned)v[2] | ((unsigned)v[3] << 16);
  o.z = (unsigned)v[4] | ((unsigned)v[5] << 16);
  o.w = (unsigned)v[6] | ((unsigned)v[7] << 16);
  *(uint4*)&Bp[(size_t)t * 8] = o;
}

// A [M x 172] bf16 -> out = A @ W + bias. 64 rows/block (4 waves x 16 rows),
// K padded to 192. LDS stride 200 ushorts (400B): 16B-aligned, bank-even
// (8 lanes per bank-quad = the wave64-b128 floor).
template<typename TAB>
__global__ __launch_bounds__(256)
void mfma_proj_kernel(const int* __restrict__ dflag,
    const u16* __restrict__ A, int M,
    const u16* __restrict__ Bp, int NT,
    const u16* __restrict__ bias1, const u16* __restrict__ bias2,
    TAB* __restrict__ out1, int N1, TAB* __restrict__ out2, int N2){
  if (*dflag != 0) return;
  __shared__ u16 xs[64][200];
  int row0 = blockIdx.x * 64;
  int tid = threadIdx.x;
  const unsigned int* A32 = (const unsigned int*)A;   // 86 uints per row
  unsigned int* xs32 = (unsigned int*)&xs[0][0];      // 100 uints per LDS row
  for (int j = tid; j < 64 * 86; j += 256){
    int r = j / 86, k2 = j % 86;
    unsigned int v = (row0 + r < M) ? A32[(size_t)(row0 + r) * 86 + k2] : 0u;
    xs32[r * 100 + k2] = v;
  }
  for (int j = tid; j < 64 * 14; j += 256){
    int r = j / 14, k2 = 86 + (j % 14);
    xs32[r * 100 + k2] = 0u;                          // zero K pad 172..199
  }
  __syncthreads();
  int lane = tid & 63, w = tid >> 6;
  int ar = 16 * w + (lane & 15);
  int kg = lane >> 4;
  bf16x8s a[6];
  #pragma unroll
  for (int s = 0; s < 6; s++)
    a[s] = *(const bf16x8s*)&xs[ar][s * 32 + kg * 8];
  int co_l = lane & 15;
  int rb = row0 + 16 * w + 4 * kg;
  for (int c = 0; c < NT; c++){
    const u16* bp = Bp + (size_t)(c * 6) * 512 + (size_t)lane * 8;
    f32x4 acc = {0.f, 0.f, 0.f, 0.f};
    #pragma unroll
    for (int s = 0; s < 6; s++){
      bf16x8s b = *(const bf16x8s*)(bp + s * 512);
      acc = __builtin_amdgcn_mfma_f32_16x16x32_bf16(a[s], b, acc, 0, 0, 0);
    }
    int co = c * 16 + co_l;
    float bv; TAB* op; size_t stride; int cc;
    if (co < N1){ bv = bits2f(bias1[co]); op = out1; stride = N1; cc = co; }
    else if (co < N1 + N2){ bv = bits2f(bias2[co - N1]); op = out2; stride = N2; cc = co - N1; }
    else continue;
    #pragma unroll
    for (int r = 0; r < 4; r++){
      int row = rb + r;
      if (row < M) OutStore<TAB>::st(op, (size_t)row * stride + cc, acc[r] + bv);
    }
  }
}

// A[r][k] = cos(utd[r]*tw[k]+tb[k]) computed into LDS as bf16; K=100 pad 128.
// LDS stride 136 ushorts (272B): 16B-aligned, bank-even.
template<typename TAB>
__global__ __launch_bounds__(256)
void mfma_time_proj_kernel(const int* __restrict__ dflag,
    const u16* __restrict__ utd, int M,
    const u16* __restrict__ Bp,
    const u16* __restrict__ tw, const u16* __restrict__ tb,
    const u16* __restrict__ bias, TAB* __restrict__ out1){
  if (*dflag != 0) return;
  __shared__ u16 xs[64][136];
  __shared__ float ts[64];
  int row0 = blockIdx.x * 64;
  int tid = threadIdx.x;
  if (tid < 64){
    int r = row0 + tid;
    ts[tid] = bits2f(utd[(r < M) ? r : (M - 1)]);
  }
  __syncthreads();
  unsigned int* xs32 = (unsigned int*)&xs[0][0];      // 68 uints per LDS row
  for (int j = tid; j < 64 * 68; j += 256){
    int r = j / 68, k2 = j % 68;
    int k = k2 * 2;
    unsigned int v = 0u;
    if (k < K_DT){
      float c0 = cosf(ts[r] * bits2f(tw[k])     + bits2f(tb[k]));
      float c1 = cosf(ts[r] * bits2f(tw[k + 1]) + bits2f(tb[k + 1]));
      v = pk2(c0, c1);
    }
    xs32[r * 68 + k2] = v;
  }
  __syncthreads();
  int lane = tid & 63, w = tid >> 6;
  int ar = 16 * w + (lane & 15);
  int kg = lane >> 4;
  bf16x8s a[4];
  #pragma unroll
  for (int s = 0; s < 4; s++)
    a[s] = *(const bf16x8s*)&xs[ar][s * 32 + kg * 8];
  int co_l = lane & 15;
  int rb = row0 + 16 * w + 4 * kg;
  for (int c = 0; c < NT_KV; c++){
    const u16* bp = Bp + (size_t)(c * 4) * 512 + (size_t)lane * 8;
    f32x4 acc = {0.f, 0.f, 0.f, 0.f};
    #pragma unroll
    for (int s = 0; s < 4; s++){
      bf16x8s b = *(const bf16x8s*)(bp + s * 512);
      acc = __builtin_amdgcn_mfma_f32_16x16x32_bf16(a[s], b, acc, 0, 0, 0);
    }
    int co = c * 16 + co_l;
    if (co >= K_DKV) continue;
    float bv = bits2f(bias[co]);
    #pragma unroll
    for (int r = 0; r < 4; r++){
      int row = rb + r;
      if (row < M) OutStore<TAB>::st(out1, (size_t)row * K_DKV + co, acc[r] + bv);
    }
  }
}

// ============================================================================
// f32-input path (want=1): keep the VALU projection kernels (insurance).
// ============================================================================
template<typename TAB, typename TIN>
__global__ __launch_bounds__(320)
void node_proj_kernel(const int* __restrict__ dflag, int want,
    const void* nodeData_v, const void* Wqn_v, const void* bqn_v,
    const void* Wkvn_v, const void* bkvn_v,
    TAB* __restrict__ qn_tab, TAB* __restrict__ kvn_tab){
  if (*dflag != want) return;
  __shared__ float xs[32][68];
  int row0 = blockIdx.x * 32;
  int tid = threadIdx.x;
  int ci = tid % 75, ri = tid / 75;
  const void* W; const TIN* B; int ldw, c0;
  if (ci < 25){ W = Wqn_v;  B = (const TIN*)bqn_v;  ldw = K_DOUT; c0 = 4*ci; }
  else        { W = Wkvn_v; B = (const TIN*)bkvn_v; ldw = K_DKV;  c0 = 4*(ci-25); }
  float acc[8][4] = {};
  #pragma unroll
  for (int c = 0; c < 3; c++){
    const int ng = (c < 2) ? 16 : 11;
    if (c > 0) __syncthreads();
    for (int idx = tid; idx < 32 * ng; idx += 320){
      int r = idx / ng, g = idx % ng;
      float4 v = Ld4<TIN>::ld(nodeData_v, (size_t)(row0 + r) * K_DN + (16*c + g) * 4);
      *(float4*)&xs[r][g * 4] = v;
    }
    __syncthreads();
    if (tid < 300){
      const float* xbase = &xs[8*ri][0];
      #pragma unroll 2
      for (int g = 0; g < ng; g++){
        int kg = (16*c + g) * 4;
        float4 w0 = Ld4<TIN>::ld(W, (size_t)(kg+0) * ldw + c0);
        float4 w1 = Ld4<TIN>::ld(W, (size_t)(kg+1) * ldw + c0);
        float4 w2 = Ld4<TIN>::ld(W, (size_t)(kg+2) * ldw + c0);
        float4 w3 = Ld4<TIN>::ld(W, (size_t)(kg+3) * ldw + c0);
        #pragma unroll
        for (int i = 0; i < 8; i++){
          float4 a = *(const float4*)(xbase + i * 68 + 4*g);
          acc[i][0] = fmaf(a.x,w0.x, fmaf(a.y,w1.x, fmaf(a.z,w2.x, fmaf(a.w,w3.x, acc[i][0]))));
          acc[i][1] = fmaf(a.x,w0.y, fmaf(a.y,w1.y, fmaf(a.z,w2.y, fmaf(a.w,w3.y, acc[i][1]))));
          acc[i][2] = fmaf(a.x,w0.z, fmaf(a.y,w1.z, fmaf(a.z,w2.z, fmaf(a.w,w3.z, acc[i][2]))));
          acc[i][3] = fmaf(a.x,w0.w, fmaf(a.y,w1.w, fmaf(a.z,w2.w, fmaf(a.w,w3.w, acc[i][3]))));
        }
      }
    }
  }
  if (tid >= 300) return;
  float b0 = t2f(B[c0+0]), b1 = t2f(B[c0+1]), b2 = t2f(B[c0+2]), b3 = t2f(B[c0+3]);
  TAB* tab = (ci < 25) ? qn_tab : kvn_tab;
  #pragma unroll
  for (int i = 0; i < 8; i++){
    size_t row = row0 + 8*ri + i;
    store4<TAB>(&tab[row * ldw + c0], acc[i][0]+b0, acc[i][1]+b1, acc[i][2]+b2, acc[i][3]+b3);
  }
}

template<typename TAB, typename TIN>
__global__ __launch_bounds__(256)
void feat_proj_kernel(const int* __restrict__ dflag, int want,
    const void* A_v, const void* W_v, const void* bias_v,
    TAB* __restrict__ out_tab){
  if (*dflag != want) return;
  __shared__ float xs[40][68];
  int row0 = blockIdx.x * 40;
  int tid = threadIdx.x;
  int ci = tid % 50, ri = tid / 50;
  int c0 = 4 * ci;
  float acc[8][4] = {};
  #pragma unroll
  for (int c = 0; c < 3; c++){
    const int ng = (c < 2) ? 16 : 11;
    if (c > 0) __syncthreads();
    for (int idx = tid; idx < 40 * ng; idx += 256){
      int r = idx / ng, g = idx % ng;
      float4 v = Ld4<TIN>::ld(A_v, (size_t)(row0 + r) * K_DN + (16*c + g) * 4);
      *(float4*)&xs[r][g * 4] = v;
    }
    __syncthreads();
    if (tid < 250){
      const float* xbase = &xs[8*ri][0];
      #pragma unroll 2
      for (int g = 0; g < ng; g++){
        int kg = (16*c + g) * 4;
        float4 w0 = Ld4<TIN>::ld(W_v, (size_t)(kg+0) * K_DKV + c0);
        float4 w1 = Ld4<TIN>::ld(W_v, (size_t)(kg+1) * K_DKV + c0);
        float4 w2 = Ld4<TIN>::ld(W_v, (size_t)(kg+2) * K_DKV + c0);
        float4 w3 = Ld4<TIN>::ld(W_v, (size_t)(kg+3) * K_DKV + c0);
        #pragma unroll
        for (int i = 0; i < 8; i++){
          float4 a = *(const float4*)(xbase + i * 68 + 4*g);
          acc[i][0] = fmaf(a.x,w0.x, fmaf(a.y,w1.x, fmaf(a.z,w2.x, fmaf(a.w,w3.x, acc[i][0]))));
          acc[i][1] = fmaf(a.x,w0.y, fmaf(a.y,w1.y, fmaf(a.z,w2.y, fmaf(a.w,w3.y, acc[i][1]))));
          acc[i][2] = fmaf(a.x,w0.z, fmaf(a.y,w1.z, fmaf(a.z,w2.z, fmaf(a.w,w3.z, acc[i][2]))));
          acc[i][3] = fmaf(a.x,w0.w, fmaf(a.y,w1.w, fmaf(a.z,w2.w, fmaf(a.w,w3.w, acc[i][3]))));
        }
      }
    }
  }
  if (tid >= 250) return;
  const TIN* B = (const TIN*)bias_v;
  float b0 = t2f(B[c0+0]), b1 = t2f(B[c0+1]), b2 = t2f(B[c0+2]), b3 = t2f(B[c0+3]);
  #pragma unroll
  for (int i = 0; i < 8; i++){
    size_t row = row0 + 8*ri + i;
    store4<TAB>(&out_tab[row * K_DKV + c0], acc[i][0]+b0, acc[i][1]+b1, acc[i][2]+b2, acc[i][3]+b3);
  }
}

template<typename TAB, typename TIN>
__global__ __launch_bounds__(256)
void time_proj_kernel(const int* __restrict__ dflag, int want,
    const void* utd_v, const void* time_w_v, const void* time_b_v,
    const void* Wkvt_v, const void* bkvt_v,
    TAB* __restrict__ kvt_tab){
  if (*dflag != want) return;
  __shared__ float xs[40][68];
  __shared__ float ts[40];
  int row0 = blockIdx.x * 40;
  int tid = threadIdx.x;
  if (tid < 40) ts[tid] = t2f(((const TIN*)utd_v)[row0 + tid]);
  __syncthreads();
  int ci = tid % 50, ri = tid / 50;
  int c0 = 4 * ci;
  float acc[8][4] = {};
  #pragma unroll
  for (int c = 0; c < 2; c++){
    const int ng = (c < 1) ? 16 : 9;
    const int nk = ng * 4;
    if (c > 0) __syncthreads();
    for (int idx = tid; idx < 40 * nk; idx += 256){
      int r = idx / nk, kloc = idx % nk;
      int k = 64*c + kloc;
      xs[r][kloc] = cosf(ts[r] * t2f(((const TIN*)time_w_v)[k]) + t2f(((const TIN*)time_b_v)[k]));
    }
    __syncthreads();
    if (tid < 250){
      const float* xbase = &xs[8*ri][0];
      #pragma unroll 2
      for (int g = 0; g < ng; g++){
        int kg = 64*c + 4*g;
        float4 w0 = Ld4<TIN>::ld(Wkvt_v, (size_t)(kg+0) * K_DKV + c0);
        float4 w1 = Ld4<TIN>::ld(Wkvt_v, (size_t)(kg+1) * K_DKV + c0);
        float4 w2 = Ld4<TIN>::ld(Wkvt_v, (size_t)(kg+2) * K_DKV + c0);
        float4 w3 = Ld4<TIN>::ld(Wkvt_v, (size_t)(kg+3) * K_DKV + c0);
        #pragma unroll
        for (int i = 0; i < 8; i++){
          float4 a = *(const float4*)(xbase + i * 68 + 4*g);
          acc[i][0] = fmaf(a.x,w0.x, fmaf(a.y,w1.x, fmaf(a.z,w2.x, fmaf(a.w,w3.x, acc[i][0]))));
          acc[i][1] = fmaf(a.x,w0.y, fmaf(a.y,w1.y, fmaf(a.z,w2.y, fmaf(a.w,w3.y, acc[i][1]))));
          acc[i][2] = fmaf(a.x,w0.z, fmaf(a.y,w1.z, fmaf(a.z,w2.z, fmaf(a.w,w3.z, acc[i][2]))));
          acc[i][3] = fmaf(a.x,w0.w, fmaf(a.y,w1.w, fmaf(a.z,w2.w, fmaf(a.w,w3.w, acc[i][3]))));
        }
      }
    }
  }
  if (tid >= 250) return;
  const TIN* B = (const TIN*)bkvt_v;
  float b0 = t2f(B[c0+0]), b1 = t2f(B[c0+1]), b2 = t2f(B[c0+2]), b3 = t2f(B[c0+3]);
  #pragma unroll
  for (int i = 0; i < 8; i++){
    size_t row = row0 + 8*ri + i;
    store4<TAB>(&kvt_tab[row * K_DKV + c0], acc[i][0]+b0, acc[i][1]+b1, acc[i][2]+b2, acc[i][3]+b3);
  }
}

// ---- CSR construction ----
__global__ void hist_kernel(const int* __restrict__ dstindex, int* __restrict__ counts){
  int e = blockIdx.x * blockDim.x + threadIdx.x;
  if (e < K_E) atomicAdd(&counts[dstindex[e]], 1);
}

__global__ void scan1_kernel(const int* __restrict__ counts, int* __restrict__ offsets,
                             int* __restrict__ bsum, int n){
  __shared__ int sd[256];
  int b = blockIdx.x, t = threadIdx.x;
  int base = b * 1024 + t * 4;
  int v0=0,v1=0,v2=0,v3=0;
  if (base+0 < n) v0 = counts[base+0];
  if (base+1 < n) v1 = counts[base+1];
  if (base+2 < n) v2 = counts[base+2];
  if (base+3 < n) v3 = counts[base+3];
  int s = v0+v1+v2+v3;
  sd[t] = s;
  __syncthreads();
  for (int off = 1; off < 256; off <<= 1){
    int tmp = (t >= off) ? sd[t-off] : 0;
    __syncthreads();
    sd[t] += tmp;
    __syncthreads();
  }
  int excl = sd[t] - s;
  if (base+0 < n) offsets[base+0] = excl;
  if (base+1 < n) offsets[base+1] = excl + v0;
  if (base+2 < n) offsets[base+2] = excl + v0 + v1;
  if (base+3 < n) offsets[base+3] = excl + v0 + v1 + v2;
  if (t == 255) bsum[b] = sd[255];
}

__global__ void scan2_kernel(int* bsum, int nb){
  if (threadIdx.x == 0 && blockIdx.x == 0){
    int run = 0;
    for (int i = 0; i < nb; i++){ int v = bsum[i]; bsum[i] = run; run += v; }
  }
}

__global__ void scan3_kernel(int* __restrict__ offsets, const int* __restrict__ bsum, int n){
  int i = blockIdx.x * blockDim.x + threadIdx.x;
  if (i < n) offsets[i] += bsum[i >> 10];
}

__global__ void scatter_kernel(const int* __restrict__ dstindex, const int* __restrict__ offsets,
                               int* __restrict__ cursor, int* __restrict__ edge_ids){
  int e = blockIdx.x * blockDim.x + threadIdx.x;
  if (e < K_E){
    int d = dstindex[e];
    int p = atomicAdd(&cursor[d], 1);
    edge_ids[offsets[d] + p] = e;
  }
}

// ---- attention: online softmax, 1 wave per dst (4 dst/block), no LDS/sync ----
template<typename TAB>
__global__ __launch_bounds__(256)
void attn_kernel(
    const int* __restrict__ reverse_nids, const int* __restrict__ reverse_eids,
    const int* __restrict__ reverse_tids,
    const int* __restrict__ dstoff, const int* __restrict__ dstcnt,
    const int* __restrict__ edge_ids,
    const TAB* __restrict__ qn_tab, const TAB* __restrict__ kvn_tab,
    const TAB* __restrict__ kve_tab, const TAB* __restrict__ kvt_tab,
    const float* __restrict__ qt, float* __restrict__ out_agg){
  int tid = threadIdx.x;
  int wave = tid >> 6;
  int l = tid & 63;
  int h = l >> 5;
  int li = l & 31;
  int dst = blockIdx.x * 4 + wave;
  int start = dstoff[dst];
  int cnt = dstcnt[dst];
  int cntw = (cnt + 1 - h) >> 1;
  bool act = (li < 25);
  int d4 = 4 * li;
  bool c0h0 = (d4+0) < 50, c1h0 = (d4+1) < 50, c2h0 = (d4+2) < 50, c3h0 = (d4+3) < 50;

  int gn = reverse_nids[dst];
  float4 q = make_float4(0.f,0.f,0.f,0.f);
  if (act){
    float4 qn = Ld4<TAB>::ld(qn_tab, (size_t)gn * K_DOUT + d4);
    float4 qtv = *(const float4*)(qt + d4);
    q.x = qn.x + qtv.x; q.y = qn.y + qtv.y; q.z = qn.z + qtv.z; q.w = qn.w + qtv.w;
  }

  float m0 = -3.0e38f, m1 = -3.0e38f, s0 = 0.f, s1 = 0.f;
  float ax = 0.f, ay = 0.f, az = 0.f, aw = 0.f;

  for (int j = 0; j < cntw; j++){
    int e   = edge_ids[start + 2*j + h];
    int nid = reverse_nids[K_NUM_DST + e];
    int eid = reverse_eids[e];
    int tde = reverse_tids[e];
    float4 kx = make_float4(0.f,0.f,0.f,0.f);
    if (act){
      float4 k1 = Ld4<TAB>::ld(kvn_tab, (size_t)nid * K_DKV + d4);
      float4 k2 = Ld4<TAB>::ld(kve_tab, (size_t)eid * K_DKV + d4);
      float4 k3 = Ld4<TAB>::ld(kvt_tab, (size_t)tde * K_DKV + d4);
      kx.x = k1.x+k2.x+k3.x; kx.y = k1.y+k2.y+k3.y; kx.z = k1.z+k2.z+k3.z; kx.w = k1.w+k2.w+k3.w;
    }
    float px = q.x*kx.x, py = q.y*kx.y, pz = q.z*kx.z, pw = q.w*kx.w;
    float p0 = (c0h0?px:0.f) + (c1h0?py:0.f) + (c2h0?pz:0.f) + (c3h0?pw:0.f);
    float p1 = (px+py+pz+pw) - p0;
    #pragma unroll
    for (int off = 16; off; off >>= 1){
      p0 += __shfl_xor(p0, off);
      p1 += __shfl_xor(p1, off);
    }
    float a0 = (p0 > 0.f) ? p0 : K_NEG_SLOPE * p0;
    float a1 = (p1 > 0.f) ? p1 : K_NEG_SLOPE * p1;
    float nm0 = fmaxf(m0, a0), nm1 = fmaxf(m1, a1);
    float al0 = __expf(m0 - nm0), al1 = __expf(m1 - nm1);
    float e0  = __expf(a0 - nm0), e1  = __expf(a1 - nm1);
    s0 = s0 * al0 + e0; s1 = s1 * al1 + e1;
    m0 = nm0; m1 = nm1;
    float4 vx = make_float4(0.f,0.f,0.f,0.f);
    if (act){
      float4 v1 = Ld4<TAB>::ld(kvn_tab, (size_t)nid * K_DKV + K_DOUT + d4);
      float4 v2 = Ld4<TAB>::ld(kve_tab, (size_t)eid * K_DKV + K_DOUT + d4);
      float4 v3 = Ld4<TAB>::ld(kvt_tab, (size_t)tde * K_DKV + K_DOUT + d4);
      vx.x = v1.x+v2.x+v3.x; vx.y = v1.y+v2.y+v3.y; vx.z = v1.z+v2.z+v3.z; vx.w = v1.w+v2.w+v3.w;
    }
    ax = ax * (c0h0?al0:al1) + (c0h0?e0:e1) * vx.x;
    ay = ay * (c1h0?al0:al1) + (c1h0?e0:e1) * vx.y;
    az = az * (c2h0?al0:al1) + (c2h0?e0:e1) * vx.z;
    aw = aw * (c3h0?al0:al1) + (c3h0?e0:e1) * vx.w;
  }

  float mo0 = __shfl_xor(m0, 32), so0 = __shfl_xor(s0, 32);
  float mo1 = __shfl_xor(m1, 32), so1 = __shfl_xor(s1, 32);
  float aox = __shfl_xor(ax, 32), aoy = __shfl_xor(ay, 32);
  float aoz = __shfl_xor(az, 32), aow = __shfl_xor(aw, 32);
  float M0 = fmaxf(m0, mo0), M1 = fmaxf(m1, mo1);
  float cs0 = __expf(m0 - M0), co0 = __expf(mo0 - M0);
  float cs1 = __expf(m1 - M1), co1 = __expf(mo1 - M1);
  float S0 = s0 * cs0 + so0 * co0;
  float S1 = s1 * cs1 + so1 * co1;
  float inv0 = (S0 > 0.f) ? 1.f / S0 : 0.f;
  float inv1 = (S1 > 0.f) ? 1.f / S1 : 0.f;
  float rx = c0h0 ? (ax*cs0 + aox*co0)*inv0 : (ax*cs1 + aox*co1)*inv1;
  float ry = c1h0 ? (ay*cs0 + aoy*co0)*inv0 : (ay*cs1 + aoy*co1)*inv1;
  float rz = c2h0 ? (az*cs0 + aoz*co0)*inv0 : (az*cs1 + aoz*co1)*inv1;
  float rw = c3h0 ? (aw*cs0 + aow*co0)*inv0 : (aw*cs1 + aow*co1)*inv1;
  if (h == 0 && act){
    float4 r; r.x=rx; r.y=ry; r.z=rz; r.w=rw;
    *(float4*)(out_agg + (size_t)dst * K_DOUT + d4) = r;
  }
}

// ---- final: relu(concat[out_agg, nodeData[gather]] @ Wout) -> LayerNorm ----
template<typename TIN>
__global__ __launch_bounds__(256)
void final_kernel(const int* __restrict__ dflag, int want,
    const float* __restrict__ out_agg,
    const void* nodeData_v, const int* __restrict__ reverse_nids,
    const void* Wout_v, const void* bout_v,
    const void* ln_g_v, const void* ln_b_v,
    void* out){
  if (*dflag != want) return;
  __shared__ float xs[32][72];
  __shared__ float part[32][25][2];
  __shared__ float stats[32][2];
  __shared__ int gnid[32];
  int dbase = blockIdx.x * 32;
  int tid = threadIdx.x;
  if (tid < 32) gnid[tid] = reverse_nids[dbase + tid];
  __syncthreads();
  int ci = tid % 25, ri = tid / 25;
  int c0 = 4 * ci;
  float acc[4][4] = {};
  #pragma unroll
  for (int c = 0; c < 4; c++){
    if (c > 0) __syncthreads();
    for (int idx = tid; idx < 32 * 17; idx += 256){
      int r = idx / 17, g = idx % 17;
      int gk = (c * 17 + g) * 4;
      float4 v;
      if (gk < 100) v = *(const float4*)(out_agg + (size_t)(dbase + r) * K_DOUT + gk);
      else          v = Ld4<TIN>::ld(nodeData_v, (size_t)gnid[r] * K_DN + (gk - 100));
      *(float4*)&xs[r][g * 4] = v;
    }
    __syncthreads();
    if (tid < 200){
      const float* xbase = &xs[4 * ri][0];
      #pragma unroll 2
      for (int g = 0; g < 17; g++){
        int kg = (c * 17 + g) * 4;
        float4 w0 = Ld4<TIN>::ld(Wout_v, (size_t)(kg+0) * K_DOUT + c0);
        float4 w1 = Ld4<TIN>::ld(Wout_v, (size_t)(kg+1) * K_DOUT + c0);
        float4 w2 = Ld4<TIN>::ld(Wout_v, (size_t)(kg+2) * K_DOUT + c0);
        float4 w3 = Ld4<TIN>::ld(Wout_v, (size_t)(kg+3) * K_DOUT + c0);
        #pragma unroll
        for (int i = 0; i < 4; i++){
          float4 a = *(const float4*)(xbase + i * 72 + 4*g);
          acc[i][0] = fmaf(a.x,w0.x, fmaf(a.y,w1.x, fmaf(a.z,w2.x, fmaf(a.w,w3.x, acc[i][0]))));
          acc[i][1] = fmaf(a.x,w0.y, fmaf(a.y,w1.y, fmaf(a.z,w2.y, fmaf(a.w,w3.y, acc[i][1]))));
          acc[i][2] = fmaf(a.x,w0.z, fmaf(a.y,w1.z, fmaf(a.z,w2.z, fmaf(a.w,w3.z, acc[i][2]))));
          acc[i][3] = fmaf(a.x,w0.w, fmaf(a.y,w1.w, fmaf(a.z,w2.w, fmaf(a.w,w3.w, acc[i][3]))));
        }
      }
    }
  }
  if (tid < 200){
    const TIN* B = (const TIN*)bout_v;
    float b0 = t2f(B[c0+0]), b1 = t2f(B[c0+1]), b2 = t2f(B[c0+2]), b3 = t2f(B[c0+3]);
    #pragma unroll
    for (int i = 0; i < 4; i++){
      acc[i][0] = fmaxf(acc[i][0]+b0, 0.f);
      acc[i][1] = fmaxf(acc[i][1]+b1, 0.f);
      acc[i][2] = fmaxf(acc[i][2]+b2, 0.f);
      acc[i][3] = fmaxf(acc[i][3]+b3, 0.f);
      float s1 = acc[i][0]+acc[i][1]+acc[i][2]+acc[i][3];
      float s2 = acc[i][0]*acc[i][0]+acc[i][1]*acc[i][1]+acc[i][2]*acc[i][2]+acc[i][3]*acc[i][3];
      part[4*ri + i][ci][0] = s1;
      part[4*ri + i][ci][1] = s2;
    }
  }
  __syncthreads();
  if (tid < 32){
    float s1 = 0.f, s2 = 0.f;
    for (int j = 0; j < 25; j++){ s1 += part[tid][j][0]; s2 += part[tid][j][1]; }
    stats[tid][0] = s1; stats[tid][1] = s2;
  }
  __syncthreads();
  if (tid < 200){
    const TIN* G = (const TIN*)ln_g_v; const TIN* Bb = (const TIN*)ln_b_v;
    float g0 = t2f(G[c0+0]), g1 = t2f(G[c0+1]), g2 = t2f(G[c0+2]), g3 = t2f(G[c0+3]);
    float lb0 = t2f(Bb[c0+0]), lb1 = t2f(Bb[c0+1]), lb2 = t2f(Bb[c0+2]), lb3 = t2f(Bb[c0+3]);
    #pragma unroll
    for (int i = 0; i < 4; i++){
      int r = 4*ri + i;
      float mu = stats[r][0] * (1.f / K_DOUT);
      float var = stats[r][1] * (1.f / K_DOUT) - mu * mu;
      float rs = rsqrtf(var + K_LN_EPS);
      size_t o = (size_t)(dbase + r) * K_DOUT + c0;
      OutStore<TIN>::st(out, o+0, (acc[i][0]-mu)*rs*g0 + lb0);
      OutStore<TIN>::st(out, o+1, (acc[i][1]-mu)*rs*g1 + lb1);
      OutStore<TIN>::st(out, o+2, (acc[i][2]-mu)*rs*g2 + lb2);
      OutStore<TIN>::st(out, o+3, (acc[i][3]-mu)*rs*g3 + lb3);
    }
  }
}

// ---- host side ----
static inline size_t al256(size_t b){ return (b + 255) & ~(size_t)255; }

#define BP_NODE_U16 ((size_t)NT_NODE * NS_NODE * 64 * 8)
#define BP_KVE_U16  ((size_t)NT_KV * NS_KVE * 64 * 8)
#define BP_KVT_U16  ((size_t)NT_KV * NS_KVT * 64 * 8)

template<typename TAB>
static void run_pipeline(void* const* d_in, void* out, char* ws, hipStream_t stream){
  const void* nodeData = d_in[0];
  const void* efeat    = d_in[1];
  const void* utd      = d_in[2];
  const int* reverse_nids = (const int*)d_in[3];
  const int* reverse_eids = (const int*)d_in[4];
  const int* reverse_tids = (const int*)d_in[5];
  const int* dstindex     = (const int*)d_in[6];
  const void* time_w = d_in[8];
  const void* time_b = d_in[9];
  const void* Wqn  = d_in[10]; const void* bqn  = d_in[11];
  const void* Wqt  = d_in[12]; const void* bqt  = d_in[13];
  const void* Wkvn = d_in[14]; const void* bkvn = d_in[15];
  const void* Wkve = d_in[16]; const void* bkve = d_in[17];
  const void* Wkvt = d_in[18]; const void* bkvt = d_in[19];
  const void* Wout = d_in[20]; const void* bout = d_in[21];
  const void* ln_g = d_in[22]; const void* ln_b = d_in[23];

  char* p = ws;
  int* dflag = (int*)p;       p += 256;
  TAB* qn_tab  = (TAB*)p; p += al256(sizeof(TAB) * (size_t)K_UN * K_DOUT);
  TAB* kvn_tab = (TAB*)p; p += al256(sizeof(TAB) * (size_t)K_UN * K_DKV);
  TAB* kve_tab = (TAB*)p; p += al256(sizeof(TAB) * (size_t)K_UE * K_DKV);
  TAB* kvt_tab = (TAB*)p; p += al256(sizeof(TAB) * (size_t)K_UT * K_DKV);
  float* out_agg = (float*)p; p += al256(sizeof(float) * (size_t)K_NUM_DST * K_DOUT);
  float* qt = (float*)p;      p += al256(sizeof(float) * K_DOUT);
  int* counts = (int*)p;      p += al256(sizeof(int) * K_NUM_DST);
  int* offsets = (int*)p;     p += al256(sizeof(int) * K_NUM_DST);
  int* cursor = (int*)p;      p += al256(sizeof(int) * K_NUM_DST);
  int* bsum = (int*)p;        p += al256(sizeof(int) * 512);
  int* edge_ids = (int*)p;    p += al256(sizeof(int) * (size_t)K_E);
  u16* bp_node = (u16*)p;     p += al256(2 * BP_NODE_U16);
  u16* bp_kve  = (u16*)p;     p += al256(2 * BP_KVE_U16);
  u16* bp_kvt  = (u16*)p;     p += al256(2 * BP_KVT_U16);

  hipMemsetAsync(dflag, 0, 256, stream);
  hipMemsetAsync(counts, 0, sizeof(int) * K_NUM_DST, stream);
  hipMemsetAsync(cursor, 0, sizeof(int) * K_NUM_DST, stream);

  detect_kernel<<<512, 256, 0, stream>>>((const u16*)nodeData, dflag);

  // f32-input variant (want=1): VALU projections (insurance path)
  qt_kernel<float><<<1, 128, 0, stream>>>(dflag, 1, time_b, Wqt, bqt, qt);
  node_proj_kernel<TAB, float><<<K_UN / 32, 320, 0, stream>>>(dflag, 1, nodeData, Wqn, bqn, Wkvn, bkvn, qn_tab, kvn_tab);
  feat_proj_kernel<TAB, float><<<K_UE / 40, 256, 0, stream>>>(dflag, 1, efeat, Wkve, bkve, kve_tab);
  time_proj_kernel<TAB, float><<<K_UT / 40, 256, 0, stream>>>(dflag, 1, utd, time_w, time_b, Wkvt, bkvt, kvt_tab);

  // bf16-input variant (want=0): ACTIVE (FETCH_SIZE=68MB = bf16 nodeData). MFMA path.
  qt_kernel<bf16><<<1, 128, 0, stream>>>(dflag, 0, time_b, Wqt, bqt, qt);
  pack_node_w_kernel<<<(NT_NODE*NS_NODE*64 + 255)/256, 256, 0, stream>>>(
      dflag, (const u16*)Wqn, (const u16*)Wkvn, bp_node);
  pack_w_kernel<<<(NT_KV*NS_KVE*64 + 255)/256, 256, 0, stream>>>(
      dflag, (const u16*)Wkve, K_DN, K_DKV, NT_KV, NS_KVE, bp_kve);
  pack_w_kernel<<<(NT_KV*NS_KVT*64 + 255)/256, 256, 0, stream>>>(
      dflag, (const u16*)Wkvt, K_DT, K_DKV, NT_KV, NS_KVT, bp_kvt);
  mfma_proj_kernel<TAB><<<K_UN / 64, 256, 0, stream>>>(
      dflag, (const u16*)nodeData, K_UN, bp_node, NT_NODE,
      (const u16*)bqn, (const u16*)bkvn, qn_tab, K_DOUT, kvn_tab, K_DKV);
  mfma_proj_kernel<TAB><<<(K_UE + 63) / 64, 256, 0, stream>>>(
      dflag, (const u16*)efeat, K_UE, bp_kve, NT_KV,
      (const u16*)bkve, (const u16*)bkve, kve_tab, K_DKV, (TAB*)nullptr, 0);
  mfma_time_proj_kernel<TAB><<<(K_UT + 63) / 64, 256, 0, stream>>>(
      dflag, (const u16*)utd, K_UT, bp_kvt,
      (const u16*)time_w, (const u16*)time_b, (const u16*)bkvt, kvt_tab);

  hist_kernel<<<(K_E + 255) / 256, 256, 0, stream>>>(dstindex, counts);
  int nb = (K_NUM_DST + 1023) / 1024;
  scan1_kernel<<<nb, 256, 0, stream>>>(counts, offsets, bsum, K_NUM_DST);
  scan2_kernel<<<1, 1, 0, stream>>>(bsum, nb);
  scan3_kernel<<<(K_NUM_DST + 255) / 256, 256, 0, stream>>>(offsets, bsum, K_NUM_DST);
  scatter_kernel<<<(K_E + 255) / 256, 256, 0, stream>>>(dstindex, offsets, cursor, edge_ids);

  attn_kernel<TAB><<<K_NUM_DST / 4, 256, 0, stream>>>(reverse_nids, reverse_eids, reverse_tids,
      offsets, counts, edge_ids, qn_tab, kvn_tab, kve_tab, kvt_tab, qt, out_agg);

  final_kernel<float><<<K_NUM_DST / 32, 256, 0, stream>>>(dflag, 1, out_agg, nodeData, reverse_nids,
      Wout, bout, ln_g, ln_b, out);
  final_kernel<bf16><<<K_NUM_DST / 32, 256, 0, stream>>>(dflag, 0, out_agg, nodeData, reverse_nids,
      Wout, bout, ln_g, ln_b, out);
}

extern "C" void kernel_launch(void* const* d_in, const int* in_sizes, int n_in,
                              void* d_out, int out_size, void* d_ws, size_t ws_size,
                              hipStream_t stream){
  (void)in_sizes; (void)n_in; (void)out_size;

  size_t fixed = 256 + al256(4ull * K_NUM_DST * K_DOUT) + al256(4 * K_DOUT)
               + 3 * al256(4 * K_NUM_DST) + al256(4 * 512) + al256(4ull * K_E)
               + al256(2 * BP_NODE_U16) + al256(2 * BP_KVE_U16) + al256(2 * BP_KVT_U16);
  size_t tab_elems = (size_t)K_UN * K_DOUT + (size_t)K_UN * K_DKV
                   + (size_t)K_UE * K_DKV + (size_t)K_UT * K_DKV;
  size_t need_f32  = fixed + tab_elems * 4 + 8192;
  size_t need_bf16 = fixed + tab_elems * 2 + 8192;

  if (ws_size >= need_f32){
    run_pipeline<float>(d_in, d_out, (char*)d_ws, stream);
  } else if (ws_size >= need_bf16){
    run_pipeline<bf16>(d_in, d_out, (char*)d_ws, stream);
  }
}